// Round 2
// baseline (337.286 us; speedup 1.0000x reference)
//
#include <hip/hip_runtime.h>
#include <hip/hip_bf16.h>
#include <math.h>

// B=32, L1=L2=512, H=768.  All-fp16 MFMA pipeline, 6 dispatches:
//   1. cvt_xy:   xh,yh = fp16(x), fp16(y)
//   2. cvt W:    Wh = fp16(W)
//   3. proj8:    Px = fp16(relu(xh@Wh^T+b)), Py same -- 256x256 tile, BK=64,
//                8-phase schedule, counted vmcnt(4), T2 XOR-swizzle, setprio.
//   4. scores_softmax: alpha = fp16(softmax(mask(Px@Py^T))), S in-register
//   5. yT:       per-batch transpose of yh
//   6. attn:     out = alpha @ yT, fp32

typedef _Float16 f16x8 __attribute__((ext_vector_type(8)));
typedef float f32x4 __attribute__((ext_vector_type(4)));

__device__ __forceinline__ void gld_lds16(const void* g, void* l) {
  __builtin_amdgcn_global_load_lds(
      (const __attribute__((address_space(1))) unsigned*)g,
      (__attribute__((address_space(3))) unsigned*)l, 16, 0, 0);
}

#define BARR()                          \
  do {                                  \
    __builtin_amdgcn_s_barrier();       \
    __builtin_amdgcn_sched_barrier(0);  \
  } while (0)
#define LGKM0()                                      \
  do {                                               \
    asm volatile("s_waitcnt lgkmcnt(0)" ::: "memory"); \
    __builtin_amdgcn_sched_barrier(0);               \
  } while (0)
#define VMW(n)                                            \
  do {                                                    \
    asm volatile("s_waitcnt vmcnt(" #n ")" ::: "memory"); \
    __builtin_amdgcn_sched_barrier(0);                    \
  } while (0)

// ---------------- fp32 -> fp16 convert: x and y in one launch -------------
__global__ __launch_bounds__(256) void cvt_xy_kernel(
    const float* __restrict__ x, const float* __restrict__ y,
    _Float16* __restrict__ xh, _Float16* __restrict__ yh) {
  const float* src = blockIdx.y ? y : x;
  _Float16* dst = blockIdx.y ? yh : xh;
  size_t i = ((size_t)blockIdx.x * 256 + threadIdx.x) * 8;
  float4 a = *(const float4*)&src[i];
  float4 b = *(const float4*)&src[i + 4];
  _Float16 h[8] = {(_Float16)a.x, (_Float16)a.y, (_Float16)a.z, (_Float16)a.w,
                   (_Float16)b.x, (_Float16)b.y, (_Float16)b.z, (_Float16)b.w};
  *(uint4*)&dst[i] = *(uint4*)h;
}

// ---------------- fp32 -> fp16 convert (W) --------------------------------
__global__ __launch_bounds__(256) void cvt_f16_kernel(
    const float* __restrict__ src, _Float16* __restrict__ dst) {
  size_t i = ((size_t)blockIdx.x * 256 + threadIdx.x) * 8;
  float4 a = *(const float4*)&src[i];
  float4 b = *(const float4*)&src[i + 4];
  _Float16 h[8] = {(_Float16)a.x, (_Float16)a.y, (_Float16)a.z, (_Float16)a.w,
                   (_Float16)b.x, (_Float16)b.y, (_Float16)b.z, (_Float16)b.w};
  *(uint4*)&dst[i] = *(uint4*)h;
}

// ======================= 8-phase 256x256 proj ==============================
// LDS layout: As[2][256][64], Bs[2][256][64] f16 (128 KiB dynamic).
// Swizzle: byte off ^= (off>>4)&0x60 (bits 9,10 -> 5,6; row bits 2,3 of the
// 128B-row layout).  Stage writes LINEAR dest, fetches the inverse-swizzled
// global 16B chunk (rule: both-sides-or-neither with global_load_lds).

__device__ __forceinline__ void stage_half(const _Float16* __restrict__ G,
                                           int grow0, int k0, _Float16* L,
                                           int w, int l) {
  // stages 128 rows x 64 cols (16 KB): rows grow0..+127, cols k0..+63
#pragma unroll
  for (int s = 0; s < 2; ++s) {
    int rb = s * 64 + w * 8;        // wave's 8-row block within the half
    int rin = rb + (l >> 3);        // this lane's dest row (0..127)
    int cp = (l & 7) ^ ((rin >> 1) & 6);  // pre-swizzled source 16B chunk
    gld_lds16(&G[(size_t)(grow0 + rin) * 768 + k0 + cp * 8],
              L + (size_t)rb * 64);  // wave-uniform linear dest
  }
}

__device__ __forceinline__ f16x8 frag_ld(const _Float16* S, int row, int colb) {
  int off = row * 128 + colb;
  off ^= (off >> 4) & 0x60;
  return *(const f16x8*)((const char*)S + off);
}

__device__ __forceinline__ void read_a(const _Float16* S, int wm, int mh,
                                       int fr, int fkg, f16x8 a[4][2]) {
#pragma unroll
  for (int f4 = 0; f4 < 4; ++f4)
#pragma unroll
    for (int ks = 0; ks < 2; ++ks)
      a[f4][ks] = frag_ld(S, wm + mh * 64 + f4 * 16 + fr, ks * 64 + fkg * 16);
}

__device__ __forceinline__ void read_b(const _Float16* S, int wn, int nh,
                                       int fr, int fkg, f16x8 b[2][2]) {
#pragma unroll
  for (int nb = 0; nb < 2; ++nb)
#pragma unroll
    for (int ks = 0; ks < 2; ++ks)
      b[nb][ks] = frag_ld(S, wn + (nh * 2 + nb) * 16 + fr, ks * 64 + fkg * 16);
}

__device__ __forceinline__ void mma_q(f16x8 a[4][2], f16x8 b[2][2],
                                      f32x4 acc[8][4], int mh, int nh) {
  __builtin_amdgcn_s_setprio(1);
#pragma unroll
  for (int f4 = 0; f4 < 4; ++f4)
#pragma unroll
    for (int nb = 0; nb < 2; ++nb)
#pragma unroll
      for (int ks = 0; ks < 2; ++ks)
        acc[mh * 4 + f4][nh * 2 + nb] = __builtin_amdgcn_mfma_f32_16x16x32_f16(
            a[f4][ks], b[nb][ks], acc[mh * 4 + f4][nh * 2 + nb], 0, 0, 0);
  __builtin_amdgcn_s_setprio(0);
}

__global__ __launch_bounds__(512, 2) void proj8_kernel(
    const _Float16* __restrict__ Xh, const _Float16* __restrict__ Yh,
    const _Float16* __restrict__ W, const float* __restrict__ bias,
    _Float16* __restrict__ Px, _Float16* __restrict__ Py) {
  const int N = 768;
  const _Float16* A = blockIdx.z ? Yh : Xh;
  _Float16* P = blockIdx.z ? Py : Px;
  extern __shared__ _Float16 smem[];
  _Float16* As0 = smem;              // [256][64]
  _Float16* As1 = smem + 16384;
  _Float16* Bs0 = smem + 32768;
  _Float16* Bs1 = smem + 49152;

  const int bm = blockIdx.x * 256, bn = blockIdx.y * 256;
  const int tid = threadIdx.x, l = tid & 63, w = tid >> 6;
  const int fr = l & 15, fkg = l >> 4;
  const int wm = (w >> 2) * 128, wn = (w & 3) * 64;

  f32x4 acc[8][4];
#pragma unroll
  for (int i = 0; i < 8; ++i)
#pragma unroll
    for (int j = 0; j < 4; ++j)
#pragma unroll
      for (int e = 0; e < 4; ++e) acc[i][j][e] = 0.f;

  // Prologue: A(0), B(0) fully + B(1) fully.  A(1) staged at p1,p2 of t=0.
  stage_half(A, bm + 0, 0, As0, w, l);
  stage_half(A, bm + 128, 0, As0 + 128 * 64, w, l);
  stage_half(W, bn + 0, 0, Bs0, w, l);
  stage_half(W, bn + 128, 0, Bs0 + 128 * 64, w, l);
  stage_half(W, bn + 0, 64, Bs1, w, l);
  stage_half(W, bn + 128, 64, Bs1 + 128 * 64, w, l);
  VMW(4);  // A(0),B(0) landed; B(1) may fly
  BARR();

  f16x8 a[4][2], b0[2][2], b1[2][2];

  for (int t = 0; t < 6; ++t) {
    const bool g = (t < 5);
    const int ka1 = (2 * t + 1) * 64, k2 = (2 * t + 2) * 64, k3 = (2 * t + 3) * 64;
    // ---- p1: slot0 Q(m0,n0); stage A(2t+1)h0 -> As1 (freed at prev p7)
    read_a(As0, wm, 0, fr, fkg, a);
    read_b(Bs0, wn, 0, fr, fkg, b0);
    stage_half(A, bm + 0, ka1, As1, w, l);
    BARR(); LGKM0();
    mma_q(a, b0, acc, 0, 0);
    BARR();
    // ---- p2: Q(m0,n1); stage A(2t+1)h1
    read_b(Bs0, wn, 1, fr, fkg, b1);
    stage_half(A, bm + 128, ka1, As1 + 128 * 64, w, l);
    BARR(); LGKM0();
    mma_q(a, b1, acc, 0, 1);
    BARR();
    // ---- p3: Q(m1,n1); stage B(2t+2)h0 -> Bs0 (B reads done at p2 barrier)
    read_a(As0, wm, 1, fr, fkg, a);
    if (g) stage_half(W, bn + 0, k2, Bs0, w, l);
    BARR(); LGKM0();
    mma_q(a, b1, acc, 1, 1);
    BARR();
    // ---- p4: Q(m1,n0); stage B(2t+2)h1; checkpoint vmcnt
    if (g) stage_half(W, bn + 128, k2, Bs0 + 128 * 64, w, l);
    BARR(); LGKM0();
    mma_q(a, b0, acc, 1, 0);
    if (g) { VMW(4); } else { VMW(0); }  // A(2t+1),B(2t+1) landed
    BARR();
    // ---- p5: slot1 Q(m0,n0); stage A(2t+2)h0 -> As0 (A reads done at p3)
    read_a(As1, wm, 0, fr, fkg, a);
    read_b(Bs1, wn, 0, fr, fkg, b0);
    if (g) stage_half(A, bm + 0, k2, As0, w, l);
    BARR(); LGKM0();
    mma_q(a, b0, acc, 0, 0);
    BARR();
    // ---- p6: Q(m0,n1); stage A(2t+2)h1
    read_b(Bs1, wn, 1, fr, fkg, b1);
    if (g) stage_half(A, bm + 128, k2, As0 + 128 * 64, w, l);
    BARR(); LGKM0();
    mma_q(a, b1, acc, 0, 1);
    BARR();
    // ---- p7: Q(m1,n1); stage B(2t+3)h0 -> Bs1 (B slot1 reads done at p6)
    read_a(As1, wm, 1, fr, fkg, a);
    if (g) stage_half(W, bn + 0, k3, Bs1, w, l);
    BARR(); LGKM0();
    mma_q(a, b1, acc, 1, 1);
    BARR();
    // ---- p8: Q(m1,n0); stage B(2t+3)h1; checkpoint vmcnt
    if (g) stage_half(W, bn + 128, k3, Bs1 + 128 * 64, w, l);
    BARR(); LGKM0();
    mma_q(a, b0, acc, 1, 0);
    if (g) VMW(4);  // A(2t+2),B(2t+2) landed for next iter's p1
    BARR();
  }

  // Epilogue: bias + relu + fp16 store (same C/D mapping as verified kernel)
#pragma unroll
  for (int mf = 0; mf < 8; ++mf)
#pragma unroll
    for (int r = 0; r < 4; ++r) {
      int m = bm + wm + mf * 16 + fkg * 4 + r;
#pragma unroll
      for (int nf = 0; nf < 4; ++nf) {
        int n = bn + wn + nf * 16 + fr;
        P[(size_t)m * N + n] = (_Float16)fmaxf(acc[mf][nf][r] + bias[n], 0.f);
      }
    }
}

// ---- fused scores+softmax: alpha[b,512,512] = softmax(mask(Px@Py^T)) -----
__global__ __launch_bounds__(512) void scores_softmax_kernel(
    const _Float16* __restrict__ Px, const _Float16* __restrict__ Py,
    const int* __restrict__ mask, _Float16* __restrict__ Alpha) {
  const int K = 768, L = 512;
  __shared__ _Float16 As[64 * 32];
  __shared__ _Float16 Bs[512 * 32];
  __shared__ float redm[8][64], reds[8][64];
  int b = blockIdx.y;
  size_t pb = (size_t)b * L * K;
  const int* mk = mask + (size_t)b * L;
  _Float16* Ab = Alpha + (size_t)b * L * L;
  int bm = blockIdx.x * 64;
  int tid = threadIdx.x, lane = tid & 63, wave = tid >> 6;
  int wn = wave * 64;
  int fr = lane & 15, fk = (lane >> 4) * 8;
  int lrow = lane >> 2, lcol = (lane & 3) << 3;

  f32x4 acc[4][4];
#pragma unroll
  for (int i = 0; i < 4; ++i)
#pragma unroll
    for (int j = 0; j < 4; ++j)
#pragma unroll
      for (int e = 0; e < 4; ++e) acc[i][j][e] = 0.f;

  for (int k0 = 0; k0 < K; k0 += 32) {
    __syncthreads();
#pragma unroll
    for (int t = 0; t < 4; ++t) {
      int row = wave * 64 + t * 16;
      gld_lds16(&Py[pb + (size_t)(row + lrow) * K + k0 + lcol], &Bs[row * 32]);
    }
    if (wave < 4) {
      int row = wave * 16;
      gld_lds16(&Px[pb + (size_t)(bm + row + lrow) * K + k0 + lcol], &As[row * 32]);
    }
    __syncthreads();
    f16x8 a[4], bb[4];
#pragma unroll
    for (int i = 0; i < 4; ++i) {
      a[i] = *(const f16x8*)&As[(i * 16 + fr) * 32 + fk];
      bb[i] = *(const f16x8*)&Bs[(wn + i * 16 + fr) * 32 + fk];
    }
#pragma unroll
    for (int i = 0; i < 4; ++i)
#pragma unroll
      for (int j = 0; j < 4; ++j)
        acc[i][j] = __builtin_amdgcn_mfma_f32_16x16x32_f16(a[i], bb[j], acc[i][j], 0, 0, 0);
  }

  int mki[4];
#pragma unroll
  for (int j = 0; j < 4; ++j) mki[j] = mk[wn + j * 16 + fr];
#pragma unroll
  for (int i = 0; i < 4; ++i)
#pragma unroll
    for (int j = 0; j < 4; ++j)
      if (mki[j]) {
#pragma unroll
        for (int r = 0; r < 4; ++r) acc[i][j][r] = -INFINITY;
      }

  int g4 = (lane >> 4) << 2;
#pragma unroll
  for (int i = 0; i < 4; ++i)
#pragma unroll
    for (int r = 0; r < 4; ++r) {
      float m = fmaxf(fmaxf(acc[i][0][r], acc[i][1][r]),
                      fmaxf(acc[i][2][r], acc[i][3][r]));
      m = fmaxf(m, __shfl_xor(m, 1));
      m = fmaxf(m, __shfl_xor(m, 2));
      m = fmaxf(m, __shfl_xor(m, 4));
      m = fmaxf(m, __shfl_xor(m, 8));
      if (fr == 0) redm[wave][i * 16 + g4 + r] = m;
    }
  __syncthreads();
  float M[4][4];
#pragma unroll
  for (int i = 0; i < 4; ++i)
#pragma unroll
    for (int r = 0; r < 4; ++r) {
      int row = i * 16 + g4 + r;
      float m = redm[0][row];
#pragma unroll
      for (int ww = 1; ww < 8; ++ww) m = fmaxf(m, redm[ww][row]);
      M[i][r] = m;
    }
#pragma unroll
  for (int i = 0; i < 4; ++i)
#pragma unroll
    for (int r = 0; r < 4; ++r) {
      float s = 0.f;
#pragma unroll
      for (int j = 0; j < 4; ++j) {
        float e = __expf(acc[i][j][r] - M[i][r]);
        acc[i][j][r] = e;
        s += e;
      }
      s += __shfl_xor(s, 1);
      s += __shfl_xor(s, 2);
      s += __shfl_xor(s, 4);
      s += __shfl_xor(s, 8);
      if (fr == 0) reds[wave][i * 16 + g4 + r] = s;
    }
  __syncthreads();
#pragma unroll
  for (int i = 0; i < 4; ++i)
#pragma unroll
    for (int r = 0; r < 4; ++r) {
      int row = i * 16 + g4 + r;
      float s = reds[0][row];
#pragma unroll
      for (int ww = 1; ww < 8; ++ww) s += reds[ww][row];
      float inv = 1.0f / s;
#pragma unroll
      for (int j = 0; j < 4; ++j)
        Ab[(size_t)(bm + row) * L + wn + j * 16 + fr] =
            (_Float16)(acc[i][j][r] * inv);
    }
}

// -------- yT: yh [b,512,768] fp16 -> yT [b,768,512] fp16 (bit moves) ------
__global__ __launch_bounds__(256) void yT_kernel(
    const _Float16* __restrict__ Yh, _Float16* __restrict__ YT) {
  __shared__ unsigned short T[64][65];
  int b = blockIdx.z;
  int n0 = blockIdx.x * 64, h0 = blockIdx.y * 64;
  const unsigned short* Yb = (const unsigned short*)Yh + (size_t)b * 512 * 768;
  unsigned short* Tb = (unsigned short*)YT + (size_t)b * 768 * 512;
  int tid = threadIdx.x;
  int r = tid >> 4, c = (tid & 15) << 2;
#pragma unroll
  for (int i = 0; i < 4; ++i) {
    int rr = r + i * 16;
    ushort4 v = *(const ushort4*)&Yb[(size_t)(n0 + rr) * 768 + h0 + c];
    T[c + 0][rr] = v.x;
    T[c + 1][rr] = v.y;
    T[c + 2][rr] = v.z;
    T[c + 3][rr] = v.w;
  }
  __syncthreads();
  int hr = tid >> 2, nc = (tid & 3) << 4;
  unsigned short tmp[16];
#pragma unroll
  for (int j = 0; j < 16; ++j) tmp[j] = T[hr][nc + j];
  unsigned short* dst = &Tb[(size_t)(h0 + hr) * 512 + n0 + nc];
  *(uint4*)&dst[0] = *(uint4*)&tmp[0];
  *(uint4*)&dst[8] = *(uint4*)&tmp[8];
}

// ---- attn: O[b,512,768] = alpha @ y, K=512, fp16 MFMA --------------------
__global__ __launch_bounds__(256) void attn_mfma_kernel(
    const _Float16* __restrict__ Alpha, const _Float16* __restrict__ YT,
    float* __restrict__ O) {
  const int L = 512, H = 768;
  __shared__ _Float16 As[128 * 32], Bs[128 * 32];
  int b = blockIdx.z;
  const _Float16* Ab = Alpha + (size_t)b * L * L;
  const _Float16* Yb = YT + (size_t)b * H * L;
  float* Ob = O + (size_t)b * L * H;
  int bm = blockIdx.x * 128, bn = blockIdx.y * 128;
  int tid = threadIdx.x, lane = tid & 63, wave = tid >> 6;
  int wm = (wave & 1) * 64, wn = (wave >> 1) * 64;
  int fr = lane & 15, fk = (lane >> 4) * 8;
  int lrow = lane >> 2, lcol = (lane & 3) << 3;

  f32x4 acc[4][4];
#pragma unroll
  for (int i = 0; i < 4; ++i)
#pragma unroll
    for (int j = 0; j < 4; ++j)
#pragma unroll
      for (int e = 0; e < 4; ++e) acc[i][j][e] = 0.f;

  for (int k0 = 0; k0 < L; k0 += 32) {
    __syncthreads();
#pragma unroll
    for (int t = 0; t < 2; ++t) {
      int row = wave * 32 + t * 16;
      gld_lds16(&Ab[(size_t)(bm + row + lrow) * L + k0 + lcol], &As[row * 32]);
      gld_lds16(&Yb[(size_t)(bn + row + lrow) * L + k0 + lcol], &Bs[row * 32]);
    }
    __syncthreads();
    f16x8 a[4], bb[4];
#pragma unroll
    for (int i = 0; i < 4; ++i) {
      a[i] = *(const f16x8*)&As[(wm + i * 16 + fr) * 32 + fk];
      bb[i] = *(const f16x8*)&Bs[(wn + i * 16 + fr) * 32 + fk];
    }
#pragma unroll
    for (int i = 0; i < 4; ++i)
#pragma unroll
      for (int j = 0; j < 4; ++j)
        acc[i][j] = __builtin_amdgcn_mfma_f32_16x16x32_f16(a[i], bb[j], acc[i][j], 0, 0, 0);
  }
#pragma unroll
  for (int i = 0; i < 4; ++i)
#pragma unroll
    for (int r = 0; r < 4; ++r) {
      int m = bm + wm + i * 16 + (lane >> 4) * 4 + r;
#pragma unroll
      for (int j = 0; j < 4; ++j) {
        int h = bn + wn + j * 16 + fr;
        Ob[(size_t)m * H + h] = acc[i][j][r];
      }
    }
}

extern "C" void kernel_launch(void* const* d_in, const int* in_sizes, int n_in,
                              void* d_out, int out_size, void* d_ws, size_t ws_size,
                              hipStream_t stream) {
  const float* x = (const float*)d_in[0];   // [32,512,768]
  const float* y = (const float*)d_in[1];   // [32,512,768]
  const int* y_mask = (const int*)d_in[2];  // [32,512]
  const float* W = (const float*)d_in[3];   // [768,768]
  const float* b = (const float*)d_in[4];   // [768]
  float* out = (float*)d_out;               // [32,512,768]

  const size_t E = (size_t)16384 * 768;     // 12,582,912 elems / fp16 plane
  _Float16* xh = (_Float16*)d_ws;           // 25.2 MB
  _Float16* yh = xh + E;                    // 25.2 MB
  _Float16* Px = yh + E;                    // 25.2 MB
  _Float16* Py = Px + E;                    // 25.2 MB
  _Float16* Wh = Py + E;                    // 1.2 MB
  _Float16* alpha = xh;                     // overlays xh (dead after proj)
  _Float16* yT = Px;                        // overlays Px (dead after scores)

  static bool attr_set = false;
  if (!attr_set) {
    hipFuncSetAttribute((const void*)proj8_kernel,
                        hipFuncAttributeMaxDynamicSharedMemorySize, 131072);
    attr_set = true;
  }

  dim3 blk(256);
  cvt_xy_kernel<<<dim3(6144, 2), blk, 0, stream>>>(x, y, xh, yh);
  cvt_f16_kernel<<<dim3(288), blk, 0, stream>>>(W, Wh);
  proj8_kernel<<<dim3(64, 3, 2), dim3(512), 131072, stream>>>(xh, yh, Wh, b, Px, Py);
  scores_softmax_kernel<<<dim3(8, 32), dim3(512), 0, stream>>>(Px, Py, y_mask, alpha);
  yT_kernel<<<dim3(8, 12, 32), blk, 0, stream>>>(yh, yT);
  attn_mfma_kernel<<<dim3(4, 6, 32), blk, 0, stream>>>(alpha, yT, out);
}

// Round 3
// 288.039 us; speedup vs baseline: 1.1710x; 1.1710x over previous
//
#include <hip/hip_runtime.h>
#include <hip/hip_bf16.h>
#include <math.h>

// B=32, L1=L2=512, H=768.  All-fp16 MFMA pipeline, 6 dispatches:
//   1. cvt_xy:   xh,yh = fp16(x), fp16(y)
//   2. cvt W:    Wh = fp16(W)
//   3. proj8:    Px = fp16(relu(xh@Wh^T+b)), Py same -- 256x128 tile, BK=64,
//                6-phase/2-K-tile schedule, counted vmcnt(2), XOR-swizzle,
//                setprio.  Per-wave tile 128x32 (acc=64) -> no spills.
//   4. scores_softmax: alpha = fp16(softmax(mask(Px@Py^T))), S in-register
//   5. yT:       per-batch transpose of yh
//   6. attn:     out = alpha @ yT, fp32

typedef _Float16 f16x8 __attribute__((ext_vector_type(8)));
typedef float f32x4 __attribute__((ext_vector_type(4)));

__device__ __forceinline__ void gld_lds16(const void* g, void* l) {
  __builtin_amdgcn_global_load_lds(
      (const __attribute__((address_space(1))) unsigned*)g,
      (__attribute__((address_space(3))) unsigned*)l, 16, 0, 0);
}

#define BARR()                          \
  do {                                  \
    __builtin_amdgcn_s_barrier();       \
    __builtin_amdgcn_sched_barrier(0);  \
  } while (0)
#define LGKM0()                                        \
  do {                                                 \
    asm volatile("s_waitcnt lgkmcnt(0)" ::: "memory"); \
    __builtin_amdgcn_sched_barrier(0);                 \
  } while (0)
#define VMW(n)                                            \
  do {                                                    \
    asm volatile("s_waitcnt vmcnt(" #n ")" ::: "memory"); \
    __builtin_amdgcn_sched_barrier(0);                    \
  } while (0)

// ---------------- fp32 -> fp16 convert: x and y in one launch -------------
__global__ __launch_bounds__(256) void cvt_xy_kernel(
    const float* __restrict__ x, const float* __restrict__ y,
    _Float16* __restrict__ xh, _Float16* __restrict__ yh) {
  const float* src = blockIdx.y ? y : x;
  _Float16* dst = blockIdx.y ? yh : xh;
  size_t i = ((size_t)blockIdx.x * 256 + threadIdx.x) * 8;
  float4 a = *(const float4*)&src[i];
  float4 b = *(const float4*)&src[i + 4];
  _Float16 h[8] = {(_Float16)a.x, (_Float16)a.y, (_Float16)a.z, (_Float16)a.w,
                   (_Float16)b.x, (_Float16)b.y, (_Float16)b.z, (_Float16)b.w};
  *(uint4*)&dst[i] = *(uint4*)h;
}

// ---------------- fp32 -> fp16 convert (W) --------------------------------
__global__ __launch_bounds__(256) void cvt_f16_kernel(
    const float* __restrict__ src, _Float16* __restrict__ dst) {
  size_t i = ((size_t)blockIdx.x * 256 + threadIdx.x) * 8;
  float4 a = *(const float4*)&src[i];
  float4 b = *(const float4*)&src[i + 4];
  _Float16 h[8] = {(_Float16)a.x, (_Float16)a.y, (_Float16)a.z, (_Float16)a.w,
                   (_Float16)b.x, (_Float16)b.y, (_Float16)b.z, (_Float16)b.w};
  *(uint4*)&dst[i] = *(uint4*)h;
}

// ======================= 8-phase 256x128 proj ==============================
// LDS: As[2][128+128][64] (64KB) + Bs[2][128][64] (32KB) = 96 KiB dynamic.
// Swizzle: byte off ^= (off>>4)&0x60 (row bits 2,3 -> chunk bits 1,2).
// Stage = linear LDS dest + inverse-swizzled global source (same involution).

// stages 128 rows x 64 cols (16 KB, 2 VMEM/wave)
__device__ __forceinline__ void stage128(const _Float16* __restrict__ G,
                                         int grow0, int k0, _Float16* L,
                                         int w, int l) {
#pragma unroll
  for (int s = 0; s < 2; ++s) {
    int rb = s * 64 + w * 8;
    int rin = rb + (l >> 3);
    int cp = (l & 7) ^ ((rin >> 1) & 6);
    gld_lds16(&G[(size_t)(grow0 + rin) * 768 + k0 + cp * 8],
              L + (size_t)rb * 64);
  }
}

__device__ __forceinline__ f16x8 frag_ld(const _Float16* S, int row, int colb) {
  int off = row * 128 + colb;
  off ^= (off >> 4) & 0x60;
  return *(const f16x8*)((const char*)S + off);
}

__device__ __forceinline__ void read_a(const _Float16* S, int wm, int mh,
                                       int fr, int fkg, f16x8 a[4][2]) {
#pragma unroll
  for (int f4 = 0; f4 < 4; ++f4)
#pragma unroll
    for (int ks = 0; ks < 2; ++ks)
      a[f4][ks] = frag_ld(S, wm + mh * 64 + f4 * 16 + fr, ks * 64 + fkg * 16);
}

__device__ __forceinline__ void read_b(const _Float16* S, int wn, int nf,
                                       int fr, int fkg, f16x8 b2[2]) {
#pragma unroll
  for (int ks = 0; ks < 2; ++ks)
    b2[ks] = frag_ld(S, wn + nf * 16 + fr, ks * 64 + fkg * 16);
}

// 8 MFMA: quadrant (mh, nf), ks OUTER (no back-to-back dependent MFMAs)
__device__ __forceinline__ void mma8(f16x8 a[4][2], f16x8 b2[2],
                                     f32x4 acc[8][2], int mh, int nf) {
#pragma unroll
  for (int ks = 0; ks < 2; ++ks)
#pragma unroll
    for (int f4 = 0; f4 < 4; ++f4)
      acc[mh * 4 + f4][nf] = __builtin_amdgcn_mfma_f32_16x16x32_f16(
          a[f4][ks], b2[ks], acc[mh * 4 + f4][nf], 0, 0, 0);
}

__global__ __launch_bounds__(512, 2) void proj8_kernel(
    const _Float16* __restrict__ Xh, const _Float16* __restrict__ Yh,
    const _Float16* __restrict__ W, const float* __restrict__ bias,
    _Float16* __restrict__ Px, _Float16* __restrict__ Py) {
  const int N = 768;
  const _Float16* A = blockIdx.z ? Yh : Xh;
  _Float16* P = blockIdx.z ? Py : Px;
  extern __shared__ _Float16 smem[];
  _Float16* As0 = smem;              // [256][64]
  _Float16* As1 = smem + 16384;      // [256][64]
  _Float16* Bs0 = smem + 32768;      // [128][64]
  _Float16* Bs1 = smem + 40960;      // [128][64]

  const int bm = blockIdx.x * 256, bn = blockIdx.y * 128;
  const int tid = threadIdx.x, l = tid & 63, w = tid >> 6;
  const int fr = l & 15, fkg = l >> 4;
  const int wm = (w >> 2) * 128, wn = (w & 3) * 32;

  f32x4 acc[8][2];
#pragma unroll
  for (int i = 0; i < 8; ++i)
#pragma unroll
    for (int j = 0; j < 2; ++j)
#pragma unroll
      for (int e = 0; e < 4; ++e) acc[i][j][e] = 0.f;

  // Prologue: A(0) (4 ops), B(0) (2), B(1) (2).  A(1) staged at p1,p2.
  stage128(A, bm + 0, 0, As0, w, l);
  stage128(A, bm + 128, 0, As0 + 8192, w, l);
  stage128(W, bn, 0, Bs0, w, l);
  stage128(W, bn, 64, Bs1, w, l);
  VMW(2);  // A(0),B(0) landed; B(1) in flight
  BARR();

  f16x8 a[4][2], b0[2], b1[2];

  for (int t = 0; t < 6; ++t) {
    const bool g = (t < 5);
    const int ko = (2 * t + 1) * 64, ke = (2 * t + 2) * 64, kb = (2 * t + 3) * 64;
    // ---- p1: Q(m0,n0) slot0; stage A(2t+1)h0 -> As1 (free since prev p78)
    read_a(As0, wm, 0, fr, fkg, a);
    read_b(Bs0, wn, 0, fr, fkg, b0);
    stage128(A, bm + 0, ko, As1, w, l);
    BARR(); LGKM0();
    __builtin_amdgcn_s_setprio(1);
    mma8(a, b0, acc, 0, 0);
    __builtin_amdgcn_s_setprio(0);
    BARR();
    // ---- p2: Q(m0,n1); stage A(2t+1)h1
    read_b(Bs0, wn, 1, fr, fkg, b1);
    stage128(A, bm + 128, ko, As1 + 8192, w, l);
    BARR(); LGKM0();
    __builtin_amdgcn_s_setprio(1);
    mma8(a, b1, acc, 0, 1);
    __builtin_amdgcn_s_setprio(0);
    BARR();
    // ---- p34: Q(m1,n1)+Q(m1,n0); stage B(2t+2)->Bs0 (reads done p2);
    //      VMW(2) waits A(2t+1)+B(2t+1) for p5
    read_a(As0, wm, 1, fr, fkg, a);
    if (g) stage128(W, bn, ke, Bs0, w, l);
    BARR(); LGKM0();
    __builtin_amdgcn_s_setprio(1);
    mma8(a, b1, acc, 1, 1);
    mma8(a, b0, acc, 1, 0);
    __builtin_amdgcn_s_setprio(0);
    if (g) { VMW(2); } else { VMW(0); }
    BARR();
    // ---- p5: Q(m0,n0) slot1; stage A(2t+2)h0 -> As0 (reads done p34)
    read_a(As1, wm, 0, fr, fkg, a);
    read_b(Bs1, wn, 0, fr, fkg, b0);
    if (g) stage128(A, bm + 0, ke, As0, w, l);
    BARR(); LGKM0();
    __builtin_amdgcn_s_setprio(1);
    mma8(a, b0, acc, 0, 0);
    __builtin_amdgcn_s_setprio(0);
    BARR();
    // ---- p6: Q(m0,n1); stage A(2t+2)h1
    read_b(Bs1, wn, 1, fr, fkg, b1);
    if (g) stage128(A, bm + 128, ke, As0 + 8192, w, l);
    BARR(); LGKM0();
    __builtin_amdgcn_s_setprio(1);
    mma8(a, b1, acc, 0, 1);
    __builtin_amdgcn_s_setprio(0);
    BARR();
    // ---- p78: Q(m1,n1)+Q(m1,n0); stage B(2t+3)->Bs1 (reads done p6);
    //      VMW(2) waits A(2t+2)+B(2t+2) for next p1
    read_a(As1, wm, 1, fr, fkg, a);
    if (g) stage128(W, bn, kb, Bs1, w, l);
    BARR(); LGKM0();
    __builtin_amdgcn_s_setprio(1);
    mma8(a, b1, acc, 1, 1);
    mma8(a, b0, acc, 1, 0);
    __builtin_amdgcn_s_setprio(0);
    if (g) { VMW(2); } else { VMW(0); }
    BARR();
  }

  // Epilogue: bias + relu + fp16 store
#pragma unroll
  for (int mf = 0; mf < 8; ++mf)
#pragma unroll
    for (int r = 0; r < 4; ++r) {
      int m = bm + wm + mf * 16 + fkg * 4 + r;
#pragma unroll
      for (int nf = 0; nf < 2; ++nf) {
        int n = bn + wn + nf * 16 + fr;
        P[(size_t)m * N + n] = (_Float16)fmaxf(acc[mf][nf][r] + bias[n], 0.f);
      }
    }
}

// ---- fused scores+softmax: alpha[b,512,512] = softmax(mask(Px@Py^T)) -----
__global__ __launch_bounds__(512) void scores_softmax_kernel(
    const _Float16* __restrict__ Px, const _Float16* __restrict__ Py,
    const int* __restrict__ mask, _Float16* __restrict__ Alpha) {
  const int K = 768, L = 512;
  __shared__ _Float16 As[64 * 32];
  __shared__ _Float16 Bs[512 * 32];
  __shared__ float redm[8][64], reds[8][64];
  int b = blockIdx.y;
  size_t pb = (size_t)b * L * K;
  const int* mk = mask + (size_t)b * L;
  _Float16* Ab = Alpha + (size_t)b * L * L;
  int bm = blockIdx.x * 64;
  int tid = threadIdx.x, lane = tid & 63, wave = tid >> 6;
  int wn = wave * 64;
  int fr = lane & 15, fk = (lane >> 4) * 8;
  int lrow = lane >> 2, lcol = (lane & 3) << 3;

  f32x4 acc[4][4];
#pragma unroll
  for (int i = 0; i < 4; ++i)
#pragma unroll
    for (int j = 0; j < 4; ++j)
#pragma unroll
      for (int e = 0; e < 4; ++e) acc[i][j][e] = 0.f;

  for (int k0 = 0; k0 < K; k0 += 32) {
    __syncthreads();
#pragma unroll
    for (int t = 0; t < 4; ++t) {
      int row = wave * 64 + t * 16;
      gld_lds16(&Py[pb + (size_t)(row + lrow) * K + k0 + lcol], &Bs[row * 32]);
    }
    if (wave < 4) {
      int row = wave * 16;
      gld_lds16(&Px[pb + (size_t)(bm + row + lrow) * K + k0 + lcol], &As[row * 32]);
    }
    __syncthreads();
    f16x8 a[4], bb[4];
#pragma unroll
    for (int i = 0; i < 4; ++i) {
      a[i] = *(const f16x8*)&As[(i * 16 + fr) * 32 + fk];
      bb[i] = *(const f16x8*)&Bs[(wn + i * 16 + fr) * 32 + fk];
    }
#pragma unroll
    for (int i = 0; i < 4; ++i)
#pragma unroll
      for (int j = 0; j < 4; ++j)
        acc[i][j] = __builtin_amdgcn_mfma_f32_16x16x32_f16(a[i], bb[j], acc[i][j], 0, 0, 0);
  }

  int mki[4];
#pragma unroll
  for (int j = 0; j < 4; ++j) mki[j] = mk[wn + j * 16 + fr];
#pragma unroll
  for (int i = 0; i < 4; ++i)
#pragma unroll
    for (int j = 0; j < 4; ++j)
      if (mki[j]) {
#pragma unroll
        for (int r = 0; r < 4; ++r) acc[i][j][r] = -INFINITY;
      }

  int g4 = (lane >> 4) << 2;
#pragma unroll
  for (int i = 0; i < 4; ++i)
#pragma unroll
    for (int r = 0; r < 4; ++r) {
      float m = fmaxf(fmaxf(acc[i][0][r], acc[i][1][r]),
                      fmaxf(acc[i][2][r], acc[i][3][r]));
      m = fmaxf(m, __shfl_xor(m, 1));
      m = fmaxf(m, __shfl_xor(m, 2));
      m = fmaxf(m, __shfl_xor(m, 4));
      m = fmaxf(m, __shfl_xor(m, 8));
      if (fr == 0) redm[wave][i * 16 + g4 + r] = m;
    }
  __syncthreads();
  float M[4][4];
#pragma unroll
  for (int i = 0; i < 4; ++i)
#pragma unroll
    for (int r = 0; r < 4; ++r) {
      int row = i * 16 + g4 + r;
      float m = redm[0][row];
#pragma unroll
      for (int ww = 1; ww < 8; ++ww) m = fmaxf(m, redm[ww][row]);
      M[i][r] = m;
    }
#pragma unroll
  for (int i = 0; i < 4; ++i)
#pragma unroll
    for (int r = 0; r < 4; ++r) {
      float s = 0.f;
#pragma unroll
      for (int j = 0; j < 4; ++j) {
        float e = __expf(acc[i][j][r] - M[i][r]);
        acc[i][j][r] = e;
        s += e;
      }
      s += __shfl_xor(s, 1);
      s += __shfl_xor(s, 2);
      s += __shfl_xor(s, 4);
      s += __shfl_xor(s, 8);
      if (fr == 0) reds[wave][i * 16 + g4 + r] = s;
    }
  __syncthreads();
#pragma unroll
  for (int i = 0; i < 4; ++i)
#pragma unroll
    for (int r = 0; r < 4; ++r) {
      int row = i * 16 + g4 + r;
      float s = reds[0][row];
#pragma unroll
      for (int ww = 1; ww < 8; ++ww) s += reds[ww][row];
      float inv = 1.0f / s;
#pragma unroll
      for (int j = 0; j < 4; ++j)
        Ab[(size_t)(bm + row) * L + wn + j * 16 + fr] =
            (_Float16)(acc[i][j][r] * inv);
    }
}

// -------- yT: yh [b,512,768] fp16 -> yT [b,768,512] fp16 (bit moves) ------
__global__ __launch_bounds__(256) void yT_kernel(
    const _Float16* __restrict__ Yh, _Float16* __restrict__ YT) {
  __shared__ unsigned short T[64][65];
  int b = blockIdx.z;
  int n0 = blockIdx.x * 64, h0 = blockIdx.y * 64;
  const unsigned short* Yb = (const unsigned short*)Yh + (size_t)b * 512 * 768;
  unsigned short* Tb = (unsigned short*)YT + (size_t)b * 768 * 512;
  int tid = threadIdx.x;
  int r = tid >> 4, c = (tid & 15) << 2;
#pragma unroll
  for (int i = 0; i < 4; ++i) {
    int rr = r + i * 16;
    ushort4 v = *(const ushort4*)&Yb[(size_t)(n0 + rr) * 768 + h0 + c];
    T[c + 0][rr] = v.x;
    T[c + 1][rr] = v.y;
    T[c + 2][rr] = v.z;
    T[c + 3][rr] = v.w;
  }
  __syncthreads();
  int hr = tid >> 2, nc = (tid & 3) << 4;
  unsigned short tmp[16];
#pragma unroll
  for (int j = 0; j < 16; ++j) tmp[j] = T[hr][nc + j];
  unsigned short* dst = &Tb[(size_t)(h0 + hr) * 512 + n0 + nc];
  *(uint4*)&dst[0] = *(uint4*)&tmp[0];
  *(uint4*)&dst[8] = *(uint4*)&tmp[8];
}

// ---- attn: O[b,512,768] = alpha @ y, K=512, fp16 MFMA --------------------
__global__ __launch_bounds__(256) void attn_mfma_kernel(
    const _Float16* __restrict__ Alpha, const _Float16* __restrict__ YT,
    float* __restrict__ O) {
  const int L = 512, H = 768;
  __shared__ _Float16 As[128 * 32], Bs[128 * 32];
  int b = blockIdx.z;
  const _Float16* Ab = Alpha + (size_t)b * L * L;
  const _Float16* Yb = YT + (size_t)b * H * L;
  float* Ob = O + (size_t)b * L * H;
  int bm = blockIdx.x * 128, bn = blockIdx.y * 128;
  int tid = threadIdx.x, lane = tid & 63, wave = tid >> 6;
  int wm = (wave & 1) * 64, wn = (wave >> 1) * 64;
  int fr = lane & 15, fk = (lane >> 4) * 8;
  int lrow = lane >> 2, lcol = (lane & 3) << 3;

  f32x4 acc[4][4];
#pragma unroll
  for (int i = 0; i < 4; ++i)
#pragma unroll
    for (int j = 0; j < 4; ++j)
#pragma unroll
      for (int e = 0; e < 4; ++e) acc[i][j][e] = 0.f;

  for (int k0 = 0; k0 < L; k0 += 32) {
    __syncthreads();
#pragma unroll
    for (int t = 0; t < 2; ++t) {
      int row = wave * 32 + t * 16;
      gld_lds16(&Ab[(size_t)(bm + row + lrow) * L + k0 + lcol], &As[row * 32]);
      gld_lds16(&Yb[(size_t)(bn + row + lrow) * L + k0 + lcol], &Bs[row * 32]);
    }
    __syncthreads();
    f16x8 a[4], bb[4];
#pragma unroll
    for (int i = 0; i < 4; ++i) {
      a[i] = *(const f16x8*)&As[(wm + i * 16 + fr) * 32 + fk];
      bb[i] = *(const f16x8*)&Bs[(wn + i * 16 + fr) * 32 + fk];
    }
#pragma unroll
    for (int i = 0; i < 4; ++i)
#pragma unroll
      for (int j = 0; j < 4; ++j)
        acc[i][j] = __builtin_amdgcn_mfma_f32_16x16x32_f16(a[i], bb[j], acc[i][j], 0, 0, 0);
  }
#pragma unroll
  for (int i = 0; i < 4; ++i)
#pragma unroll
    for (int r = 0; r < 4; ++r) {
      int m = bm + wm + i * 16 + (lane >> 4) * 4 + r;
#pragma unroll
      for (int j = 0; j < 4; ++j) {
        int h = bn + wn + j * 16 + fr;
        Ob[(size_t)m * H + h] = acc[i][j][r];
      }
    }
}

extern "C" void kernel_launch(void* const* d_in, const int* in_sizes, int n_in,
                              void* d_out, int out_size, void* d_ws, size_t ws_size,
                              hipStream_t stream) {
  const float* x = (const float*)d_in[0];   // [32,512,768]
  const float* y = (const float*)d_in[1];   // [32,512,768]
  const int* y_mask = (const int*)d_in[2];  // [32,512]
  const float* W = (const float*)d_in[3];   // [768,768]
  const float* b = (const float*)d_in[4];   // [768]
  float* out = (float*)d_out;               // [32,512,768]

  const size_t E = (size_t)16384 * 768;     // 12,582,912 elems / fp16 plane
  _Float16* xh = (_Float16*)d_ws;           // 25.2 MB
  _Float16* yh = xh + E;                    // 25.2 MB
  _Float16* Px = yh + E;                    // 25.2 MB
  _Float16* Py = Px + E;                    // 25.2 MB
  _Float16* Wh = Py + E;                    // 1.2 MB
  _Float16* alpha = xh;                     // overlays xh (dead after proj)
  _Float16* yT = Px;                        // overlays Px (dead after scores)

  static bool attr_set = false;
  if (!attr_set) {
    hipFuncSetAttribute((const void*)proj8_kernel,
                        hipFuncAttributeMaxDynamicSharedMemorySize, 98304);
    attr_set = true;
  }

  dim3 blk(256);
  cvt_xy_kernel<<<dim3(6144, 2), blk, 0, stream>>>(x, y, xh, yh);
  cvt_f16_kernel<<<dim3(288), blk, 0, stream>>>(W, Wh);
  proj8_kernel<<<dim3(64, 6, 2), dim3(512), 98304, stream>>>(xh, yh, Wh, b, Px, Py);
  scores_softmax_kernel<<<dim3(8, 32), dim3(512), 0, stream>>>(Px, Py, y_mask, alpha);
  yT_kernel<<<dim3(8, 12, 32), blk, 0, stream>>>(yh, yT);
  attn_mfma_kernel<<<dim3(4, 6, 32), blk, 0, stream>>>(alpha, yT, out);
}

// Round 4
// 283.980 us; speedup vs baseline: 1.1877x; 1.0143x over previous
//
#include <hip/hip_runtime.h>
#include <hip/hip_bf16.h>
#include <math.h>

// B=32, L1=L2=512, H=768.  All-fp16 MFMA pipeline, 5 dispatches:
//   1. cvt_xW:   xh = fp16(x), Wh = fp16(W)      (1-D grid, 6144+288 blocks)
//   2. cvt_y_yT: yh = fp16(y)  AND  yT = transpose(fp16(y))  (one pass)
//   3. proj:     Px = fp16(relu(xh@Wh^T+b)), Py same  (2-phase 128*2, z-fused)
//   4. scores_softmax: alpha = fp16(softmax(mask(Px@Py^T))), S in-register
//   5. attn:     out = alpha @ yT, fp32

typedef _Float16 f16x8 __attribute__((ext_vector_type(8)));
typedef float f32x4 __attribute__((ext_vector_type(4)));

__device__ __forceinline__ void gld_lds16(const void* g, void* l) {
  __builtin_amdgcn_global_load_lds(
      (const __attribute__((address_space(1))) unsigned*)g,
      (__attribute__((address_space(3))) unsigned*)l, 16, 0, 0);
}

// ---------------- fp32 -> fp16 convert: x (6144 blocks) + W (288) ---------
__global__ __launch_bounds__(256) void cvt_xW_kernel(
    const float* __restrict__ x, const float* __restrict__ W,
    _Float16* __restrict__ xh, _Float16* __restrict__ Wh) {
  int bid = blockIdx.x;
  const float* src;
  _Float16* dst;
  size_t i;
  if (bid < 6144) {
    src = x; dst = xh;
    i = ((size_t)bid * 256 + threadIdx.x) * 8;
  } else {
    src = W; dst = Wh;
    i = ((size_t)(bid - 6144) * 256 + threadIdx.x) * 8;
  }
  float4 a = *(const float4*)&src[i];
  float4 b = *(const float4*)&src[i + 4];
  _Float16 h[8] = {(_Float16)a.x, (_Float16)a.y, (_Float16)a.z, (_Float16)a.w,
                   (_Float16)b.x, (_Float16)b.y, (_Float16)b.z, (_Float16)b.w};
  *(uint4*)&dst[i] = *(uint4*)h;
}

// ---- y: fp32 -> fp16 row-major (yh) AND fp16 transposed (yT), one pass ----
// 64x64 tile per block; LDS-transposed for the yT write.
__global__ __launch_bounds__(256) void cvt_y_yT_kernel(
    const float* __restrict__ Y, _Float16* __restrict__ Yh,
    _Float16* __restrict__ YT) {
  __shared__ unsigned short T[64][65];
  int b = blockIdx.z;
  int n0 = blockIdx.x * 64, h0 = blockIdx.y * 64;
  const float* Yb = Y + (size_t)b * 512 * 768;
  unsigned short* Hb = (unsigned short*)Yh + (size_t)b * 512 * 768;
  unsigned short* Tb = (unsigned short*)YT + (size_t)b * 768 * 512;
  int tid = threadIdx.x;
  int r = tid >> 4, c = (tid & 15) << 2;
#pragma unroll
  for (int i = 0; i < 4; ++i) {
    int rr = r + i * 16;
    float4 v = *(const float4*)&Yb[(size_t)(n0 + rr) * 768 + h0 + c];
    _Float16 h[4] = {(_Float16)v.x, (_Float16)v.y, (_Float16)v.z, (_Float16)v.w};
    unsigned short* hu = (unsigned short*)h;
    T[c + 0][rr] = hu[0];
    T[c + 1][rr] = hu[1];
    T[c + 2][rr] = hu[2];
    T[c + 3][rr] = hu[3];
    *(ushort4*)&Hb[(size_t)(n0 + rr) * 768 + h0 + c] = *(ushort4*)hu;
  }
  __syncthreads();
  int hr = tid >> 2, nc = (tid & 3) << 4;
  unsigned short tmp[16];
#pragma unroll
  for (int j = 0; j < 16; ++j) tmp[j] = T[hr][nc + j];
  unsigned short* dst = &Tb[(size_t)(h0 + hr) * 512 + n0 + nc];
  *(uint4*)&dst[0] = *(uint4*)&tmp[0];
  *(uint4*)&dst[8] = *(uint4*)&tmp[8];
}

// ---- proj: P[16384,768] = fp16(relu(A @ W^T + b)), K=768, NT fp16 GEMM ----
// blockIdx.z: 0 -> (xh -> Px), 1 -> (yh -> Py)
__global__ __launch_bounds__(256) void proj_mfma_kernel(
    const _Float16* __restrict__ Xh, const _Float16* __restrict__ Yh,
    const _Float16* __restrict__ W, const float* __restrict__ bias,
    _Float16* __restrict__ Px, _Float16* __restrict__ Py) {
  const int K = 768, N = 768;
  const _Float16* A = blockIdx.z ? Yh : Xh;
  _Float16* P = blockIdx.z ? Py : Px;
  __shared__ _Float16 As[128 * 32], Bs[128 * 32];
  int bm = blockIdx.x * 128, bn = blockIdx.y * 128;
  int tid = threadIdx.x, lane = tid & 63, wave = tid >> 6;
  int wm = (wave & 1) * 64, wn = (wave >> 1) * 64;
  int fr = lane & 15, fk = (lane >> 4) * 8;
  int lrow = lane >> 2, lcol = (lane & 3) << 3;

  f32x4 acc[4][4];
#pragma unroll
  for (int i = 0; i < 4; ++i)
#pragma unroll
    for (int j = 0; j < 4; ++j)
#pragma unroll
      for (int e = 0; e < 4; ++e) acc[i][j][e] = 0.f;

  for (int k0 = 0; k0 < K; k0 += 32) {
    __syncthreads();
#pragma unroll
    for (int t = 0; t < 2; ++t) {
      int row = wave * 32 + t * 16;
      gld_lds16(&A[(size_t)(bm + row + lrow) * K + k0 + lcol], &As[row * 32]);
      gld_lds16(&W[(size_t)(bn + row + lrow) * K + k0 + lcol], &Bs[row * 32]);
    }
    __syncthreads();
    f16x8 a[4], bb[4];
#pragma unroll
    for (int i = 0; i < 4; ++i) {
      a[i] = *(const f16x8*)&As[(wm + i * 16 + fr) * 32 + fk];
      bb[i] = *(const f16x8*)&Bs[(wn + i * 16 + fr) * 32 + fk];
    }
#pragma unroll
    for (int i = 0; i < 4; ++i)
#pragma unroll
      for (int j = 0; j < 4; ++j)
        acc[i][j] = __builtin_amdgcn_mfma_f32_16x16x32_f16(a[i], bb[j], acc[i][j], 0, 0, 0);
  }
#pragma unroll
  for (int i = 0; i < 4; ++i)
#pragma unroll
    for (int r = 0; r < 4; ++r) {
      int m = bm + wm + i * 16 + (lane >> 4) * 4 + r;
#pragma unroll
      for (int j = 0; j < 4; ++j) {
        int n = bn + wn + j * 16 + fr;
        P[(size_t)m * N + n] = (_Float16)fmaxf(acc[i][j][r] + bias[n], 0.f);
      }
    }
}

// ---- fused scores+softmax: alpha[b,512,512] = softmax(mask(Px@Py^T)) -----
__global__ __launch_bounds__(512) void scores_softmax_kernel(
    const _Float16* __restrict__ Px, const _Float16* __restrict__ Py,
    const int* __restrict__ mask, _Float16* __restrict__ Alpha) {
  const int K = 768, L = 512;
  __shared__ _Float16 As[64 * 32];
  __shared__ _Float16 Bs[512 * 32];
  __shared__ float redm[8][64], reds[8][64];
  int b = blockIdx.y;
  size_t pb = (size_t)b * L * K;
  const int* mk = mask + (size_t)b * L;
  _Float16* Ab = Alpha + (size_t)b * L * L;
  int bm = blockIdx.x * 64;
  int tid = threadIdx.x, lane = tid & 63, wave = tid >> 6;
  int wn = wave * 64;
  int fr = lane & 15, fk = (lane >> 4) * 8;
  int lrow = lane >> 2, lcol = (lane & 3) << 3;

  f32x4 acc[4][4];
#pragma unroll
  for (int i = 0; i < 4; ++i)
#pragma unroll
    for (int j = 0; j < 4; ++j)
#pragma unroll
      for (int e = 0; e < 4; ++e) acc[i][j][e] = 0.f;

  for (int k0 = 0; k0 < K; k0 += 32) {
    __syncthreads();
#pragma unroll
    for (int t = 0; t < 4; ++t) {
      int row = wave * 64 + t * 16;
      gld_lds16(&Py[pb + (size_t)(row + lrow) * K + k0 + lcol], &Bs[row * 32]);
    }
    if (wave < 4) {
      int row = wave * 16;
      gld_lds16(&Px[pb + (size_t)(bm + row + lrow) * K + k0 + lcol], &As[row * 32]);
    }
    __syncthreads();
    f16x8 a[4], bb[4];
#pragma unroll
    for (int i = 0; i < 4; ++i) {
      a[i] = *(const f16x8*)&As[(i * 16 + fr) * 32 + fk];
      bb[i] = *(const f16x8*)&Bs[(wn + i * 16 + fr) * 32 + fk];
    }
#pragma unroll
    for (int i = 0; i < 4; ++i)
#pragma unroll
      for (int j = 0; j < 4; ++j)
        acc[i][j] = __builtin_amdgcn_mfma_f32_16x16x32_f16(a[i], bb[j], acc[i][j], 0, 0, 0);
  }

  int mki[4];
#pragma unroll
  for (int j = 0; j < 4; ++j) mki[j] = mk[wn + j * 16 + fr];
#pragma unroll
  for (int i = 0; i < 4; ++i)
#pragma unroll
    for (int j = 0; j < 4; ++j)
      if (mki[j]) {
#pragma unroll
        for (int r = 0; r < 4; ++r) acc[i][j][r] = -INFINITY;
      }

  int g4 = (lane >> 4) << 2;
#pragma unroll
  for (int i = 0; i < 4; ++i)
#pragma unroll
    for (int r = 0; r < 4; ++r) {
      float m = fmaxf(fmaxf(acc[i][0][r], acc[i][1][r]),
                      fmaxf(acc[i][2][r], acc[i][3][r]));
      m = fmaxf(m, __shfl_xor(m, 1));
      m = fmaxf(m, __shfl_xor(m, 2));
      m = fmaxf(m, __shfl_xor(m, 4));
      m = fmaxf(m, __shfl_xor(m, 8));
      if (fr == 0) redm[wave][i * 16 + g4 + r] = m;
    }
  __syncthreads();
  float M[4][4];
#pragma unroll
  for (int i = 0; i < 4; ++i)
#pragma unroll
    for (int r = 0; r < 4; ++r) {
      int row = i * 16 + g4 + r;
      float m = redm[0][row];
#pragma unroll
      for (int ww = 1; ww < 8; ++ww) m = fmaxf(m, redm[ww][row]);
      M[i][r] = m;
    }
#pragma unroll
  for (int i = 0; i < 4; ++i)
#pragma unroll
    for (int r = 0; r < 4; ++r) {
      float s = 0.f;
#pragma unroll
      for (int j = 0; j < 4; ++j) {
        float e = __expf(acc[i][j][r] - M[i][r]);
        acc[i][j][r] = e;
        s += e;
      }
      s += __shfl_xor(s, 1);
      s += __shfl_xor(s, 2);
      s += __shfl_xor(s, 4);
      s += __shfl_xor(s, 8);
      if (fr == 0) reds[wave][i * 16 + g4 + r] = s;
    }
  __syncthreads();
#pragma unroll
  for (int i = 0; i < 4; ++i)
#pragma unroll
    for (int r = 0; r < 4; ++r) {
      int row = i * 16 + g4 + r;
      float s = reds[0][row];
#pragma unroll
      for (int ww = 1; ww < 8; ++ww) s += reds[ww][row];
      float inv = 1.0f / s;
#pragma unroll
      for (int j = 0; j < 4; ++j)
        Ab[(size_t)(bm + row) * L + wn + j * 16 + fr] =
            (_Float16)(acc[i][j][r] * inv);
    }
}

// ---- attn: O[b,512,768] = alpha @ y, K=512, fp16 MFMA --------------------
__global__ __launch_bounds__(256) void attn_mfma_kernel(
    const _Float16* __restrict__ Alpha, const _Float16* __restrict__ YT,
    float* __restrict__ O) {
  const int L = 512, H = 768;
  __shared__ _Float16 As[128 * 32], Bs[128 * 32];
  int b = blockIdx.z;
  const _Float16* Ab = Alpha + (size_t)b * L * L;
  const _Float16* Yb = YT + (size_t)b * H * L;
  float* Ob = O + (size_t)b * L * H;
  int bm = blockIdx.x * 128, bn = blockIdx.y * 128;
  int tid = threadIdx.x, lane = tid & 63, wave = tid >> 6;
  int wm = (wave & 1) * 64, wn = (wave >> 1) * 64;
  int fr = lane & 15, fk = (lane >> 4) * 8;
  int lrow = lane >> 2, lcol = (lane & 3) << 3;

  f32x4 acc[4][4];
#pragma unroll
  for (int i = 0; i < 4; ++i)
#pragma unroll
    for (int j = 0; j < 4; ++j)
#pragma unroll
      for (int e = 0; e < 4; ++e) acc[i][j][e] = 0.f;

  for (int k0 = 0; k0 < L; k0 += 32) {
    __syncthreads();
#pragma unroll
    for (int t = 0; t < 2; ++t) {
      int row = wave * 32 + t * 16;
      gld_lds16(&Ab[(size_t)(bm + row + lrow) * L + k0 + lcol], &As[row * 32]);
      gld_lds16(&Yb[(size_t)(bn + row + lrow) * L + k0 + lcol], &Bs[row * 32]);
    }
    __syncthreads();
    f16x8 a[4], bb[4];
#pragma unroll
    for (int i = 0; i < 4; ++i) {
      a[i] = *(const f16x8*)&As[(wm + i * 16 + fr) * 32 + fk];
      bb[i] = *(const f16x8*)&Bs[(wn + i * 16 + fr) * 32 + fk];
    }
#pragma unroll
    for (int i = 0; i < 4; ++i)
#pragma unroll
      for (int j = 0; j < 4; ++j)
        acc[i][j] = __builtin_amdgcn_mfma_f32_16x16x32_f16(a[i], bb[j], acc[i][j], 0, 0, 0);
  }
#pragma unroll
  for (int i = 0; i < 4; ++i)
#pragma unroll
    for (int r = 0; r < 4; ++r) {
      int m = bm + wm + i * 16 + (lane >> 4) * 4 + r;
#pragma unroll
      for (int j = 0; j < 4; ++j) {
        int h = bn + wn + j * 16 + fr;
        Ob[(size_t)m * H + h] = acc[i][j][r];
      }
    }
}

extern "C" void kernel_launch(void* const* d_in, const int* in_sizes, int n_in,
                              void* d_out, int out_size, void* d_ws, size_t ws_size,
                              hipStream_t stream) {
  const float* x = (const float*)d_in[0];   // [32,512,768]
  const float* y = (const float*)d_in[1];   // [32,512,768]
  const int* y_mask = (const int*)d_in[2];  // [32,512]
  const float* W = (const float*)d_in[3];   // [768,768]
  const float* b = (const float*)d_in[4];   // [768]
  float* out = (float*)d_out;               // [32,512,768]

  const size_t E = (size_t)16384 * 768;     // 12,582,912 elems / fp16 plane
  _Float16* xh = (_Float16*)d_ws;           // 25.2 MB
  _Float16* yh = xh + E;                    // 25.2 MB
  _Float16* Px = yh + E;                    // 25.2 MB
  _Float16* Py = Px + E;                    // 25.2 MB
  _Float16* Wh = Py + E;                    // 1.2 MB
  _Float16* yT = Wh + (size_t)768 * 768;    // 25.2 MB (own buffer; total 127 MB)
  _Float16* alpha = xh;                     // overlays xh (dead after proj)

  dim3 blk(256);
  cvt_xW_kernel<<<dim3(6144 + 288), blk, 0, stream>>>(x, W, xh, Wh);
  cvt_y_yT_kernel<<<dim3(8, 12, 32), blk, 0, stream>>>(y, yh, yT);
  proj_mfma_kernel<<<dim3(128, 6, 2), blk, 0, stream>>>(xh, yh, Wh, b, Px, Py);
  scores_softmax_kernel<<<dim3(8, 32), dim3(512), 0, stream>>>(Px, Py, y_mask, alpha);
  attn_mfma_kernel<<<dim3(4, 6, 32), blk, 0, stream>>>(alpha, yT, out);
}

// Round 5
// 273.913 us; speedup vs baseline: 1.2314x; 1.0368x over previous
//
#include <hip/hip_runtime.h>
#include <hip/hip_bf16.h>
#include <math.h>

// B=32, L1=L2=512, H=768.  All-fp16 MFMA pipeline, 5 dispatches:
//   1. cvt_xW:   xh = fp16(x), Wh = fp16(W)      (1-D grid, 6144+288 blocks)
//   2. cvt_y_yT: yh = fp16(y)  AND  yT = transpose(fp16(y))  (one pass)
//   3. proj:     Px = fp16(relu(xh@Wh^T+b)), Py same  (2-phase 128^2, z-fused)
//   4. scores_softmax: alpha = fp16(softmax(mask(Px@Py^T))), S in-register
//      XCD-swizzled 1-D grid: all 8 blocks of a batch land on one XCD
//      (Py L2-resident once instead of 8 HBM fetches).
//   5. attn:     out = alpha @ yT, fp32 -- same per-batch XCD co-location.

typedef _Float16 f16x8 __attribute__((ext_vector_type(8)));
typedef float f32x4 __attribute__((ext_vector_type(4)));

__device__ __forceinline__ void gld_lds16(const void* g, void* l) {
  __builtin_amdgcn_global_load_lds(
      (const __attribute__((address_space(1))) unsigned*)g,
      (__attribute__((address_space(3))) unsigned*)l, 16, 0, 0);
}

// ---------------- fp32 -> fp16 convert: x (6144 blocks) + W (288) ---------
__global__ __launch_bounds__(256) void cvt_xW_kernel(
    const float* __restrict__ x, const float* __restrict__ W,
    _Float16* __restrict__ xh, _Float16* __restrict__ Wh) {
  int bid = blockIdx.x;
  const float* src;
  _Float16* dst;
  size_t i;
  if (bid < 6144) {
    src = x; dst = xh;
    i = ((size_t)bid * 256 + threadIdx.x) * 8;
  } else {
    src = W; dst = Wh;
    i = ((size_t)(bid - 6144) * 256 + threadIdx.x) * 8;
  }
  float4 a = *(const float4*)&src[i];
  float4 b = *(const float4*)&src[i + 4];
  _Float16 h[8] = {(_Float16)a.x, (_Float16)a.y, (_Float16)a.z, (_Float16)a.w,
                   (_Float16)b.x, (_Float16)b.y, (_Float16)b.z, (_Float16)b.w};
  *(uint4*)&dst[i] = *(uint4*)h;
}

// ---- y: fp32 -> fp16 row-major (yh) AND fp16 transposed (yT), one pass ----
__global__ __launch_bounds__(256) void cvt_y_yT_kernel(
    const float* __restrict__ Y, _Float16* __restrict__ Yh,
    _Float16* __restrict__ YT) {
  __shared__ unsigned short T[64][65];
  int b = blockIdx.z;
  int n0 = blockIdx.x * 64, h0 = blockIdx.y * 64;
  const float* Yb = Y + (size_t)b * 512 * 768;
  unsigned short* Hb = (unsigned short*)Yh + (size_t)b * 512 * 768;
  unsigned short* Tb = (unsigned short*)YT + (size_t)b * 768 * 512;
  int tid = threadIdx.x;
  int r = tid >> 4, c = (tid & 15) << 2;
#pragma unroll
  for (int i = 0; i < 4; ++i) {
    int rr = r + i * 16;
    float4 v = *(const float4*)&Yb[(size_t)(n0 + rr) * 768 + h0 + c];
    _Float16 h[4] = {(_Float16)v.x, (_Float16)v.y, (_Float16)v.z, (_Float16)v.w};
    unsigned short* hu = (unsigned short*)h;
    T[c + 0][rr] = hu[0];
    T[c + 1][rr] = hu[1];
    T[c + 2][rr] = hu[2];
    T[c + 3][rr] = hu[3];
    *(ushort4*)&Hb[(size_t)(n0 + rr) * 768 + h0 + c] = *(ushort4*)hu;
  }
  __syncthreads();
  int hr = tid >> 2, nc = (tid & 3) << 4;
  unsigned short tmp[16];
#pragma unroll
  for (int j = 0; j < 16; ++j) tmp[j] = T[hr][nc + j];
  unsigned short* dst = &Tb[(size_t)(h0 + hr) * 512 + n0 + nc];
  *(uint4*)&dst[0] = *(uint4*)&tmp[0];
  *(uint4*)&dst[8] = *(uint4*)&tmp[8];
}

// ---- proj: P[16384,768] = fp16(relu(A @ W^T + b)), K=768, NT fp16 GEMM ----
__global__ __launch_bounds__(256) void proj_mfma_kernel(
    const _Float16* __restrict__ Xh, const _Float16* __restrict__ Yh,
    const _Float16* __restrict__ W, const float* __restrict__ bias,
    _Float16* __restrict__ Px, _Float16* __restrict__ Py) {
  const int K = 768, N = 768;
  const _Float16* A = blockIdx.z ? Yh : Xh;
  _Float16* P = blockIdx.z ? Py : Px;
  __shared__ _Float16 As[128 * 32], Bs[128 * 32];
  int bm = blockIdx.x * 128, bn = blockIdx.y * 128;
  int tid = threadIdx.x, lane = tid & 63, wave = tid >> 6;
  int wm = (wave & 1) * 64, wn = (wave >> 1) * 64;
  int fr = lane & 15, fk = (lane >> 4) * 8;
  int lrow = lane >> 2, lcol = (lane & 3) << 3;

  f32x4 acc[4][4];
#pragma unroll
  for (int i = 0; i < 4; ++i)
#pragma unroll
    for (int j = 0; j < 4; ++j)
#pragma unroll
      for (int e = 0; e < 4; ++e) acc[i][j][e] = 0.f;

  for (int k0 = 0; k0 < K; k0 += 32) {
    __syncthreads();
#pragma unroll
    for (int t = 0; t < 2; ++t) {
      int row = wave * 32 + t * 16;
      gld_lds16(&A[(size_t)(bm + row + lrow) * K + k0 + lcol], &As[row * 32]);
      gld_lds16(&W[(size_t)(bn + row + lrow) * K + k0 + lcol], &Bs[row * 32]);
    }
    __syncthreads();
    f16x8 a[4], bb[4];
#pragma unroll
    for (int i = 0; i < 4; ++i) {
      a[i] = *(const f16x8*)&As[(wm + i * 16 + fr) * 32 + fk];
      bb[i] = *(const f16x8*)&Bs[(wn + i * 16 + fr) * 32 + fk];
    }
#pragma unroll
    for (int i = 0; i < 4; ++i)
#pragma unroll
      for (int j = 0; j < 4; ++j)
        acc[i][j] = __builtin_amdgcn_mfma_f32_16x16x32_f16(a[i], bb[j], acc[i][j], 0, 0, 0);
  }
#pragma unroll
  for (int i = 0; i < 4; ++i)
#pragma unroll
    for (int r = 0; r < 4; ++r) {
      int m = bm + wm + i * 16 + (lane >> 4) * 4 + r;
#pragma unroll
      for (int j = 0; j < 4; ++j) {
        int n = bn + wn + j * 16 + fr;
        P[(size_t)m * N + n] = (_Float16)fmaxf(acc[i][j][r] + bias[n], 0.f);
      }
    }
}

// ---- fused scores+softmax: alpha[b,512,512] = softmax(mask(Px@Py^T)) -----
// 1-D grid of 256; decode so all 8 blocks of batch b share XCD (id%8 == b%8).
__global__ __launch_bounds__(512) void scores_softmax_kernel(
    const _Float16* __restrict__ Px, const _Float16* __restrict__ Py,
    const int* __restrict__ mask, _Float16* __restrict__ Alpha) {
  const int K = 768, L = 512;
  __shared__ _Float16 As[64 * 32];
  __shared__ _Float16 Bs[512 * 32];
  __shared__ float redm[8][64], reds[8][64];
  int g = blockIdx.x;
  int xr = g & 7, k = g >> 3;            // k in [0,32)
  int b = (k >> 3) * 8 + xr;             // batch: id%8 == b%8 -> one XCD
  int bm = (k & 7) * 64;                 // row tile
  size_t pb = (size_t)b * L * K;
  const int* mk = mask + (size_t)b * L;
  _Float16* Ab = Alpha + (size_t)b * L * L;
  int tid = threadIdx.x, lane = tid & 63, wave = tid >> 6;
  int wn = wave * 64;
  int fr = lane & 15, fk = (lane >> 4) * 8;
  int lrow = lane >> 2, lcol = (lane & 3) << 3;

  f32x4 acc[4][4];
#pragma unroll
  for (int i = 0; i < 4; ++i)
#pragma unroll
    for (int j = 0; j < 4; ++j)
#pragma unroll
      for (int e = 0; e < 4; ++e) acc[i][j][e] = 0.f;

  for (int k0 = 0; k0 < K; k0 += 32) {
    __syncthreads();
#pragma unroll
    for (int t = 0; t < 4; ++t) {
      int row = wave * 64 + t * 16;
      gld_lds16(&Py[pb + (size_t)(row + lrow) * K + k0 + lcol], &Bs[row * 32]);
    }
    if (wave < 4) {
      int row = wave * 16;
      gld_lds16(&Px[pb + (size_t)(bm + row + lrow) * K + k0 + lcol], &As[row * 32]);
    }
    __syncthreads();
    f16x8 a[4], bb[4];
#pragma unroll
    for (int i = 0; i < 4; ++i) {
      a[i] = *(const f16x8*)&As[(i * 16 + fr) * 32 + fk];
      bb[i] = *(const f16x8*)&Bs[(wn + i * 16 + fr) * 32 + fk];
    }
#pragma unroll
    for (int i = 0; i < 4; ++i)
#pragma unroll
      for (int j = 0; j < 4; ++j)
        acc[i][j] = __builtin_amdgcn_mfma_f32_16x16x32_f16(a[i], bb[j], acc[i][j], 0, 0, 0);
  }

  int mki[4];
#pragma unroll
  for (int j = 0; j < 4; ++j) mki[j] = mk[wn + j * 16 + fr];
#pragma unroll
  for (int i = 0; i < 4; ++i)
#pragma unroll
    for (int j = 0; j < 4; ++j)
      if (mki[j]) {
#pragma unroll
        for (int r = 0; r < 4; ++r) acc[i][j][r] = -INFINITY;
      }

  int g4 = (lane >> 4) << 2;
#pragma unroll
  for (int i = 0; i < 4; ++i)
#pragma unroll
    for (int r = 0; r < 4; ++r) {
      float m = fmaxf(fmaxf(acc[i][0][r], acc[i][1][r]),
                      fmaxf(acc[i][2][r], acc[i][3][r]));
      m = fmaxf(m, __shfl_xor(m, 1));
      m = fmaxf(m, __shfl_xor(m, 2));
      m = fmaxf(m, __shfl_xor(m, 4));
      m = fmaxf(m, __shfl_xor(m, 8));
      if (fr == 0) redm[wave][i * 16 + g4 + r] = m;
    }
  __syncthreads();
  float M[4][4];
#pragma unroll
  for (int i = 0; i < 4; ++i)
#pragma unroll
    for (int r = 0; r < 4; ++r) {
      int row = i * 16 + g4 + r;
      float m = redm[0][row];
#pragma unroll
      for (int ww = 1; ww < 8; ++ww) m = fmaxf(m, redm[ww][row]);
      M[i][r] = m;
    }
#pragma unroll
  for (int i = 0; i < 4; ++i)
#pragma unroll
    for (int r = 0; r < 4; ++r) {
      float s = 0.f;
#pragma unroll
      for (int j = 0; j < 4; ++j) {
        float e = __expf(acc[i][j][r] - M[i][r]);
        acc[i][j][r] = e;
        s += e;
      }
      s += __shfl_xor(s, 1);
      s += __shfl_xor(s, 2);
      s += __shfl_xor(s, 4);
      s += __shfl_xor(s, 8);
      if (fr == 0) reds[wave][i * 16 + g4 + r] = s;
    }
  __syncthreads();
#pragma unroll
  for (int i = 0; i < 4; ++i)
#pragma unroll
    for (int r = 0; r < 4; ++r) {
      int row = i * 16 + g4 + r;
      float s = reds[0][row];
#pragma unroll
      for (int ww = 1; ww < 8; ++ww) s += reds[ww][row];
      float inv = 1.0f / s;
#pragma unroll
      for (int j = 0; j < 4; ++j)
        Ab[(size_t)(bm + row) * L + wn + j * 16 + fr] =
            (_Float16)(acc[i][j][r] * inv);
    }
}

// ---- attn: O[b,512,768] = alpha @ y, K=512, fp16 MFMA --------------------
// 1-D grid of 768; all 24 blocks of batch b co-located on XCD b%8.
__global__ __launch_bounds__(256) void attn_mfma_kernel(
    const _Float16* __restrict__ Alpha, const _Float16* __restrict__ YT,
    float* __restrict__ O) {
  const int L = 512, H = 768;
  __shared__ _Float16 As[128 * 32], Bs[128 * 32];
  int g = blockIdx.x;
  int xr = g & 7, k = g >> 3;            // k in [0,96)
  int b = (k / 24) * 8 + xr;             // batch: id%8 == b%8 -> one XCD
  int j24 = k % 24;
  int bm = (j24 & 3) * 128, bn = (j24 >> 2) * 128;
  const _Float16* Ab = Alpha + (size_t)b * L * L;
  const _Float16* Yb = YT + (size_t)b * H * L;
  float* Ob = O + (size_t)b * L * H;
  int tid = threadIdx.x, lane = tid & 63, wave = tid >> 6;
  int wm = (wave & 1) * 64, wn = (wave >> 1) * 64;
  int fr = lane & 15, fk = (lane >> 4) * 8;
  int lrow = lane >> 2, lcol = (lane & 3) << 3;

  f32x4 acc[4][4];
#pragma unroll
  for (int i = 0; i < 4; ++i)
#pragma unroll
    for (int j = 0; j < 4; ++j)
#pragma unroll
      for (int e = 0; e < 4; ++e) acc[i][j][e] = 0.f;

  for (int k0 = 0; k0 < L; k0 += 32) {
    __syncthreads();
#pragma unroll
    for (int t = 0; t < 2; ++t) {
      int row = wave * 32 + t * 16;
      gld_lds16(&Ab[(size_t)(bm + row + lrow) * L + k0 + lcol], &As[row * 32]);
      gld_lds16(&Yb[(size_t)(bn + row + lrow) * L + k0 + lcol], &Bs[row * 32]);
    }
    __syncthreads();
    f16x8 a[4], bb[4];
#pragma unroll
    for (int i = 0; i < 4; ++i) {
      a[i] = *(const f16x8*)&As[(wm + i * 16 + fr) * 32 + fk];
      bb[i] = *(const f16x8*)&Bs[(wn + i * 16 + fr) * 32 + fk];
    }
#pragma unroll
    for (int i = 0; i < 4; ++i)
#pragma unroll
      for (int j = 0; j < 4; ++j)
        acc[i][j] = __builtin_amdgcn_mfma_f32_16x16x32_f16(a[i], bb[j], acc[i][j], 0, 0, 0);
  }
#pragma unroll
  for (int i = 0; i < 4; ++i)
#pragma unroll
    for (int r = 0; r < 4; ++r) {
      int m = bm + wm + i * 16 + (lane >> 4) * 4 + r;
#pragma unroll
      for (int j = 0; j < 4; ++j) {
        int h = bn + wn + j * 16 + fr;
        Ob[(size_t)m * H + h] = acc[i][j][r];
      }
    }
}

extern "C" void kernel_launch(void* const* d_in, const int* in_sizes, int n_in,
                              void* d_out, int out_size, void* d_ws, size_t ws_size,
                              hipStream_t stream) {
  const float* x = (const float*)d_in[0];   // [32,512,768]
  const float* y = (const float*)d_in[1];   // [32,512,768]
  const int* y_mask = (const int*)d_in[2];  // [32,512]
  const float* W = (const float*)d_in[3];   // [768,768]
  const float* b = (const float*)d_in[4];   // [768]
  float* out = (float*)d_out;               // [32,512,768]

  const size_t E = (size_t)16384 * 768;     // 12,582,912 elems / fp16 plane
  _Float16* xh = (_Float16*)d_ws;           // 25.2 MB
  _Float16* yh = xh + E;                    // 25.2 MB
  _Float16* Px = yh + E;                    // 25.2 MB
  _Float16* Py = Px + E;                    // 25.2 MB
  _Float16* Wh = Py + E;                    // 1.2 MB
  _Float16* yT = Wh + (size_t)768 * 768;    // 25.2 MB (own buffer; total 127 MB)
  _Float16* alpha = xh;                     // overlays xh (dead after proj)

  dim3 blk(256);
  cvt_xW_kernel<<<dim3(6144 + 288), blk, 0, stream>>>(x, W, xh, Wh);
  cvt_y_yT_kernel<<<dim3(8, 12, 32), blk, 0, stream>>>(y, yh, yT);
  proj_mfma_kernel<<<dim3(128, 6, 2), blk, 0, stream>>>(xh, yh, Wh, b, Px, Py);
  scores_softmax_kernel<<<dim3(256), dim3(512), 0, stream>>>(Px, Py, y_mask, alpha);
  attn_mfma_kernel<<<dim3(768), blk, 0, stream>>>(alpha, yT, out);
}

// Round 6
// 270.645 us; speedup vs baseline: 1.2462x; 1.0121x over previous
//
#include <hip/hip_runtime.h>
#include <hip/hip_bf16.h>
#include <math.h>

// B=32, L1=L2=512, H=768.  All-fp16 MFMA pipeline, 5 dispatches:
//   1. cvt_xW:   xh = fp16(x), Wh = fp16(W)
//   2. cvt_y_yT: yh = fp16(y) AND yT = transpose(fp16(y)) (one pass)
//   3. proj8:    Px = fp16(relu(xh@Wh^T+b)), Py same -- 256x128 tile, BK=64,
//                8-phase counted-vmcnt schedule; 3-bit XOR bank swizzle
//                (off ^= (row&7)<<4 on reads; source chunk ^ (row&7) on
//                staging -- same involution both sides, linear gld_lds dest).
//   4. scores_softmax: alpha = fp16(softmax(mask(Px@Py^T))), S in-register,
//                per-batch XCD co-location.
//   5. attn:     out = alpha @ yT, fp32, per-batch XCD co-location.

typedef _Float16 f16x8 __attribute__((ext_vector_type(8)));
typedef float f32x4 __attribute__((ext_vector_type(4)));

__device__ __forceinline__ void gld_lds16(const void* g, void* l) {
  __builtin_amdgcn_global_load_lds(
      (const __attribute__((address_space(1))) unsigned*)g,
      (__attribute__((address_space(3))) unsigned*)l, 16, 0, 0);
}

#define BARR()                          \
  do {                                  \
    __builtin_amdgcn_s_barrier();       \
    __builtin_amdgcn_sched_barrier(0);  \
  } while (0)
#define LGKM0()                                        \
  do {                                                 \
    asm volatile("s_waitcnt lgkmcnt(0)" ::: "memory"); \
    __builtin_amdgcn_sched_barrier(0);                 \
  } while (0)
#define VMW(n)                                            \
  do {                                                    \
    asm volatile("s_waitcnt vmcnt(" #n ")" ::: "memory"); \
    __builtin_amdgcn_sched_barrier(0);                    \
  } while (0)

// ---------------- fp32 -> fp16 convert: x (6144 blocks) + W (288) ---------
__global__ __launch_bounds__(256) void cvt_xW_kernel(
    const float* __restrict__ x, const float* __restrict__ W,
    _Float16* __restrict__ xh, _Float16* __restrict__ Wh) {
  int bid = blockIdx.x;
  const float* src;
  _Float16* dst;
  size_t i;
  if (bid < 6144) {
    src = x; dst = xh;
    i = ((size_t)bid * 256 + threadIdx.x) * 8;
  } else {
    src = W; dst = Wh;
    i = ((size_t)(bid - 6144) * 256 + threadIdx.x) * 8;
  }
  float4 a = *(const float4*)&src[i];
  float4 b = *(const float4*)&src[i + 4];
  _Float16 h[8] = {(_Float16)a.x, (_Float16)a.y, (_Float16)a.z, (_Float16)a.w,
                   (_Float16)b.x, (_Float16)b.y, (_Float16)b.z, (_Float16)b.w};
  *(uint4*)&dst[i] = *(uint4*)h;
}

// ---- y: fp32 -> fp16 row-major (yh) AND fp16 transposed (yT), one pass ----
__global__ __launch_bounds__(256) void cvt_y_yT_kernel(
    const float* __restrict__ Y, _Float16* __restrict__ Yh,
    _Float16* __restrict__ YT) {
  __shared__ unsigned short T[64][65];
  int b = blockIdx.z;
  int n0 = blockIdx.x * 64, h0 = blockIdx.y * 64;
  const float* Yb = Y + (size_t)b * 512 * 768;
  unsigned short* Hb = (unsigned short*)Yh + (size_t)b * 512 * 768;
  unsigned short* Tb = (unsigned short*)YT + (size_t)b * 768 * 512;
  int tid = threadIdx.x;
  int r = tid >> 4, c = (tid & 15) << 2;
#pragma unroll
  for (int i = 0; i < 4; ++i) {
    int rr = r + i * 16;
    float4 v = *(const float4*)&Yb[(size_t)(n0 + rr) * 768 + h0 + c];
    _Float16 h[4] = {(_Float16)v.x, (_Float16)v.y, (_Float16)v.z, (_Float16)v.w};
    unsigned short* hu = (unsigned short*)h;
    T[c + 0][rr] = hu[0];
    T[c + 1][rr] = hu[1];
    T[c + 2][rr] = hu[2];
    T[c + 3][rr] = hu[3];
    *(ushort4*)&Hb[(size_t)(n0 + rr) * 768 + h0 + c] = *(ushort4*)hu;
  }
  __syncthreads();
  int hr = tid >> 2, nc = (tid & 3) << 4;
  unsigned short tmp[16];
#pragma unroll
  for (int j = 0; j < 16; ++j) tmp[j] = T[hr][nc + j];
  unsigned short* dst = &Tb[(size_t)(h0 + hr) * 512 + n0 + nc];
  *(uint4*)&dst[0] = *(uint4*)&tmp[0];
  *(uint4*)&dst[8] = *(uint4*)&tmp[8];
}

// ======================= 8-phase 256x128 proj ==============================
// LDS: As[2][256][64] (64KB) + Bs[2][128][64] (32KB) = 96 KiB dynamic.
// 128B rows.  Bank fix: LDS[r][c16] holds global chunk c16 ^ (r&7); reads
// XOR the same bits back.  16 lanes reading rows r..r+15 at one column now
// hit 8 distinct 4-bank groups (2-way residual = free).

__device__ __forceinline__ void stage128(const _Float16* __restrict__ G,
                                         int grow0, int k0, _Float16* L,
                                         int w, int l) {
#pragma unroll
  for (int s = 0; s < 2; ++s) {
    int rb = s * 64 + w * 8;
    int rin = rb + (l >> 3);
    int cp = (l & 7) ^ (rin & 7);  // inverse-swizzled source 16B chunk
    gld_lds16(&G[(size_t)(grow0 + rin) * 768 + k0 + cp * 8],
              L + (size_t)rb * 64);  // wave-uniform linear dest
  }
}

__device__ __forceinline__ f16x8 frag_ld(const _Float16* S, int row, int colb) {
  int off = row * 128 + colb;
  off ^= (row & 7) << 4;  // 3-bit involution: row bits 0-2 -> chunk bits 4-6
  return *(const f16x8*)((const char*)S + off);
}

__device__ __forceinline__ void read_a(const _Float16* S, int wm, int mh,
                                       int fr, int fkg, f16x8 a[4][2]) {
#pragma unroll
  for (int f4 = 0; f4 < 4; ++f4)
#pragma unroll
    for (int ks = 0; ks < 2; ++ks)
      a[f4][ks] = frag_ld(S, wm + mh * 64 + f4 * 16 + fr, ks * 64 + fkg * 16);
}

__device__ __forceinline__ void read_b(const _Float16* S, int wn, int nf,
                                       int fr, int fkg, f16x8 b2[2]) {
#pragma unroll
  for (int ks = 0; ks < 2; ++ks)
    b2[ks] = frag_ld(S, wn + nf * 16 + fr, ks * 64 + fkg * 16);
}

// 8 MFMA: quadrant (mh, nf), ks OUTER (no back-to-back dependent MFMAs)
__device__ __forceinline__ void mma8(f16x8 a[4][2], f16x8 b2[2],
                                     f32x4 acc[8][2], int mh, int nf) {
#pragma unroll
  for (int ks = 0; ks < 2; ++ks)
#pragma unroll
    for (int f4 = 0; f4 < 4; ++f4)
      acc[mh * 4 + f4][nf] = __builtin_amdgcn_mfma_f32_16x16x32_f16(
          a[f4][ks], b2[ks], acc[mh * 4 + f4][nf], 0, 0, 0);
}

__global__ __launch_bounds__(512, 2) void proj8_kernel(
    const _Float16* __restrict__ Xh, const _Float16* __restrict__ Yh,
    const _Float16* __restrict__ W, const float* __restrict__ bias,
    _Float16* __restrict__ Px, _Float16* __restrict__ Py) {
  const int N = 768;
  const _Float16* A = blockIdx.z ? Yh : Xh;
  _Float16* P = blockIdx.z ? Py : Px;
  extern __shared__ _Float16 smem[];
  _Float16* As0 = smem;              // [256][64]
  _Float16* As1 = smem + 16384;      // [256][64]
  _Float16* Bs0 = smem + 32768;      // [128][64]
  _Float16* Bs1 = smem + 40960;      // [128][64]

  const int bm = blockIdx.x * 256, bn = blockIdx.y * 128;
  const int tid = threadIdx.x, l = tid & 63, w = tid >> 6;
  const int fr = l & 15, fkg = l >> 4;
  const int wm = (w >> 2) * 128, wn = (w & 3) * 32;

  f32x4 acc[8][2];
#pragma unroll
  for (int i = 0; i < 8; ++i)
#pragma unroll
    for (int j = 0; j < 2; ++j)
#pragma unroll
      for (int e = 0; e < 4; ++e) acc[i][j][e] = 0.f;

  // Prologue: A(0) (4 ops), B(0) (2), B(1) (2).  A(1) staged at p1,p2.
  stage128(A, bm + 0, 0, As0, w, l);
  stage128(A, bm + 128, 0, As0 + 8192, w, l);
  stage128(W, bn, 0, Bs0, w, l);
  stage128(W, bn, 64, Bs1, w, l);
  VMW(2);  // A(0),B(0) landed; B(1) in flight
  BARR();

  f16x8 a[4][2], b0[2], b1[2];

  for (int t = 0; t < 6; ++t) {
    const bool g = (t < 5);
    const int ko = (2 * t + 1) * 64, ke = (2 * t + 2) * 64, kb = (2 * t + 3) * 64;
    // ---- p1: Q(m0,n0) slot0; stage A(2t+1)h0 -> As1 (free since prev p78)
    read_a(As0, wm, 0, fr, fkg, a);
    read_b(Bs0, wn, 0, fr, fkg, b0);
    stage128(A, bm + 0, ko, As1, w, l);
    BARR(); LGKM0();
    __builtin_amdgcn_s_setprio(1);
    mma8(a, b0, acc, 0, 0);
    __builtin_amdgcn_s_setprio(0);
    BARR();
    // ---- p2: Q(m0,n1); stage A(2t+1)h1
    read_b(Bs0, wn, 1, fr, fkg, b1);
    stage128(A, bm + 128, ko, As1 + 8192, w, l);
    BARR(); LGKM0();
    __builtin_amdgcn_s_setprio(1);
    mma8(a, b1, acc, 0, 1);
    __builtin_amdgcn_s_setprio(0);
    BARR();
    // ---- p34: Q(m1,n1)+Q(m1,n0); stage B(2t+2)->Bs0 (reads done p2);
    //      VMW(2) leaves B(2t+2) in flight, drains A(2t+1)+B(2t+1)
    read_a(As0, wm, 1, fr, fkg, a);
    if (g) stage128(W, bn, ke, Bs0, w, l);
    BARR(); LGKM0();
    __builtin_amdgcn_s_setprio(1);
    mma8(a, b1, acc, 1, 1);
    mma8(a, b0, acc, 1, 0);
    __builtin_amdgcn_s_setprio(0);
    if (g) { VMW(2); } else { VMW(0); }
    BARR();
    // ---- p5: Q(m0,n0) slot1; stage A(2t+2)h0 -> As0 (reads done p34)
    read_a(As1, wm, 0, fr, fkg, a);
    read_b(Bs1, wn, 0, fr, fkg, b0);
    if (g) stage128(A, bm + 0, ke, As0, w, l);
    BARR(); LGKM0();
    __builtin_amdgcn_s_setprio(1);
    mma8(a, b0, acc, 0, 0);
    __builtin_amdgcn_s_setprio(0);
    BARR();
    // ---- p6: Q(m0,n1); stage A(2t+2)h1
    read_b(Bs1, wn, 1, fr, fkg, b1);
    if (g) stage128(A, bm + 128, ke, As0 + 8192, w, l);
    BARR(); LGKM0();
    __builtin_amdgcn_s_setprio(1);
    mma8(a, b1, acc, 0, 1);
    __builtin_amdgcn_s_setprio(0);
    BARR();
    // ---- p78: Q(m1,n1)+Q(m1,n0); stage B(2t+3)->Bs1 (reads done p6);
    //      VMW(2) drains A(2t+2)+B(2t+2) for next iter's p1
    read_a(As1, wm, 1, fr, fkg, a);
    if (g) stage128(W, bn, kb, Bs1, w, l);
    BARR(); LGKM0();
    __builtin_amdgcn_s_setprio(1);
    mma8(a, b1, acc, 1, 1);
    mma8(a, b0, acc, 1, 0);
    __builtin_amdgcn_s_setprio(0);
    if (g) { VMW(2); } else { VMW(0); }
    BARR();
  }

  // Epilogue: bias + relu + fp16 store
#pragma unroll
  for (int mf = 0; mf < 8; ++mf)
#pragma unroll
    for (int r = 0; r < 4; ++r) {
      int m = bm + wm + mf * 16 + fkg * 4 + r;
#pragma unroll
      for (int nf = 0; nf < 2; ++nf) {
        int n = bn + wn + nf * 16 + fr;
        P[(size_t)m * N + n] = (_Float16)fmaxf(acc[mf][nf][r] + bias[n], 0.f);
      }
    }
}

// ---- fused scores+softmax: alpha[b,512,512] = softmax(mask(Px@Py^T)) -----
// 1-D grid of 256; decode so all 8 blocks of batch b share XCD (id%8 == b%8).
__global__ __launch_bounds__(512) void scores_softmax_kernel(
    const _Float16* __restrict__ Px, const _Float16* __restrict__ Py,
    const int* __restrict__ mask, _Float16* __restrict__ Alpha) {
  const int K = 768, L = 512;
  __shared__ _Float16 As[64 * 32];
  __shared__ _Float16 Bs[512 * 32];
  __shared__ float redm[8][64], reds[8][64];
  int g = blockIdx.x;
  int xr = g & 7, k = g >> 3;            // k in [0,32)
  int b = (k >> 3) * 8 + xr;             // batch: id%8 == b%8 -> one XCD
  int bm = (k & 7) * 64;                 // row tile
  size_t pb = (size_t)b * L * K;
  const int* mk = mask + (size_t)b * L;
  _Float16* Ab = Alpha + (size_t)b * L * L;
  int tid = threadIdx.x, lane = tid & 63, wave = tid >> 6;
  int wn = wave * 64;
  int fr = lane & 15, fk = (lane >> 4) * 8;
  int lrow = lane >> 2, lcol = (lane & 3) << 3;

  f32x4 acc[4][4];
#pragma unroll
  for (int i = 0; i < 4; ++i)
#pragma unroll
    for (int j = 0; j < 4; ++j)
#pragma unroll
      for (int e = 0; e < 4; ++e) acc[i][j][e] = 0.f;

  for (int k0 = 0; k0 < K; k0 += 32) {
    __syncthreads();
#pragma unroll
    for (int t = 0; t < 4; ++t) {
      int row = wave * 64 + t * 16;
      gld_lds16(&Py[pb + (size_t)(row + lrow) * K + k0 + lcol], &Bs[row * 32]);
    }
    if (wave < 4) {
      int row = wave * 16;
      gld_lds16(&Px[pb + (size_t)(bm + row + lrow) * K + k0 + lcol], &As[row * 32]);
    }
    __syncthreads();
    f16x8 a[4], bb[4];
#pragma unroll
    for (int i = 0; i < 4; ++i) {
      a[i] = *(const f16x8*)&As[(i * 16 + fr) * 32 + fk];
      bb[i] = *(const f16x8*)&Bs[(wn + i * 16 + fr) * 32 + fk];
    }
#pragma unroll
    for (int i = 0; i < 4; ++i)
#pragma unroll
      for (int j = 0; j < 4; ++j)
        acc[i][j] = __builtin_amdgcn_mfma_f32_16x16x32_f16(a[i], bb[j], acc[i][j], 0, 0, 0);
  }

  int mki[4];
#pragma unroll
  for (int j = 0; j < 4; ++j) mki[j] = mk[wn + j * 16 + fr];
#pragma unroll
  for (int i = 0; i < 4; ++i)
#pragma unroll
    for (int j = 0; j < 4; ++j)
      if (mki[j]) {
#pragma unroll
        for (int r = 0; r < 4; ++r) acc[i][j][r] = -INFINITY;
      }

  int g4 = (lane >> 4) << 2;
#pragma unroll
  for (int i = 0; i < 4; ++i)
#pragma unroll
    for (int r = 0; r < 4; ++r) {
      float m = fmaxf(fmaxf(acc[i][0][r], acc[i][1][r]),
                      fmaxf(acc[i][2][r], acc[i][3][r]));
      m = fmaxf(m, __shfl_xor(m, 1));
      m = fmaxf(m, __shfl_xor(m, 2));
      m = fmaxf(m, __shfl_xor(m, 4));
      m = fmaxf(m, __shfl_xor(m, 8));
      if (fr == 0) redm[wave][i * 16 + g4 + r] = m;
    }
  __syncthreads();
  float M[4][4];
#pragma unroll
  for (int i = 0; i < 4; ++i)
#pragma unroll
    for (int r = 0; r < 4; ++r) {
      int row = i * 16 + g4 + r;
      float m = redm[0][row];
#pragma unroll
      for (int ww = 1; ww < 8; ++ww) m = fmaxf(m, redm[ww][row]);
      M[i][r] = m;
    }
#pragma unroll
  for (int i = 0; i < 4; ++i)
#pragma unroll
    for (int r = 0; r < 4; ++r) {
      float s = 0.f;
#pragma unroll
      for (int j = 0; j < 4; ++j) {
        float e = __expf(acc[i][j][r] - M[i][r]);
        acc[i][j][r] = e;
        s += e;
      }
      s += __shfl_xor(s, 1);
      s += __shfl_xor(s, 2);
      s += __shfl_xor(s, 4);
      s += __shfl_xor(s, 8);
      if (fr == 0) reds[wave][i * 16 + g4 + r] = s;
    }
  __syncthreads();
#pragma unroll
  for (int i = 0; i < 4; ++i)
#pragma unroll
    for (int r = 0; r < 4; ++r) {
      int row = i * 16 + g4 + r;
      float s = reds[0][row];
#pragma unroll
      for (int ww = 1; ww < 8; ++ww) s += reds[ww][row];
      float inv = 1.0f / s;
#pragma unroll
      for (int j = 0; j < 4; ++j)
        Ab[(size_t)(bm + row) * L + wn + j * 16 + fr] =
            (_Float16)(acc[i][j][r] * inv);
    }
}

// ---- attn: O[b,512,768] = alpha @ y, K=512, fp16 MFMA --------------------
// 1-D grid of 768; all 24 blocks of batch b co-located on XCD b%8.
__global__ __launch_bounds__(256) void attn_mfma_kernel(
    const _Float16* __restrict__ Alpha, const _Float16* __restrict__ YT,
    float* __restrict__ O) {
  const int L = 512, H = 768;
  __shared__ _Float16 As[128 * 32], Bs[128 * 32];
  int g = blockIdx.x;
  int xr = g & 7, k = g >> 3;            // k in [0,96)
  int b = (k / 24) * 8 + xr;             // batch: id%8 == b%8 -> one XCD
  int j24 = k % 24;
  int bm = (j24 & 3) * 128, bn = (j24 >> 2) * 128;
  const _Float16* Ab = Alpha + (size_t)b * L * L;
  const _Float16* Yb = YT + (size_t)b * H * L;
  float* Ob = O + (size_t)b * L * H;
  int tid = threadIdx.x, lane = tid & 63, wave = tid >> 6;
  int wm = (wave & 1) * 64, wn = (wave >> 1) * 64;
  int fr = lane & 15, fk = (lane >> 4) * 8;
  int lrow = lane >> 2, lcol = (lane & 3) << 3;

  f32x4 acc[4][4];
#pragma unroll
  for (int i = 0; i < 4; ++i)
#pragma unroll
    for (int j = 0; j < 4; ++j)
#pragma unroll
      for (int e = 0; e < 4; ++e) acc[i][j][e] = 0.f;

  for (int k0 = 0; k0 < L; k0 += 32) {
    __syncthreads();
#pragma unroll
    for (int t = 0; t < 2; ++t) {
      int row = wave * 32 + t * 16;
      gld_lds16(&Ab[(size_t)(bm + row + lrow) * L + k0 + lcol], &As[row * 32]);
      gld_lds16(&Yb[(size_t)(bn + row + lrow) * L + k0 + lcol], &Bs[row * 32]);
    }
    __syncthreads();
    f16x8 a[4], bb[4];
#pragma unroll
    for (int i = 0; i < 4; ++i) {
      a[i] = *(const f16x8*)&As[(wm + i * 16 + fr) * 32 + fk];
      bb[i] = *(const f16x8*)&Bs[(wn + i * 16 + fr) * 32 + fk];
    }
#pragma unroll
    for (int i = 0; i < 4; ++i)
#pragma unroll
      for (int j = 0; j < 4; ++j)
        acc[i][j] = __builtin_amdgcn_mfma_f32_16x16x32_f16(a[i], bb[j], acc[i][j], 0, 0, 0);
  }
#pragma unroll
  for (int i = 0; i < 4; ++i)
#pragma unroll
    for (int r = 0; r < 4; ++r) {
      int m = bm + wm + i * 16 + (lane >> 4) * 4 + r;
#pragma unroll
      for (int j = 0; j < 4; ++j) {
        int h = bn + wn + j * 16 + fr;
        Ob[(size_t)m * H + h] = acc[i][j][r];
      }
    }
}

extern "C" void kernel_launch(void* const* d_in, const int* in_sizes, int n_in,
                              void* d_out, int out_size, void* d_ws, size_t ws_size,
                              hipStream_t stream) {
  const float* x = (const float*)d_in[0];   // [32,512,768]
  const float* y = (const float*)d_in[1];   // [32,512,768]
  const int* y_mask = (const int*)d_in[2];  // [32,512]
  const float* W = (const float*)d_in[3];   // [768,768]
  const float* b = (const float*)d_in[4];   // [768]
  float* out = (float*)d_out;               // [32,512,768]

  const size_t E = (size_t)16384 * 768;     // 12,582,912 elems / fp16 plane
  _Float16* xh = (_Float16*)d_ws;           // 25.2 MB
  _Float16* yh = xh + E;                    // 25.2 MB
  _Float16* Px = yh + E;                    // 25.2 MB
  _Float16* Py = Px + E;                    // 25.2 MB
  _Float16* Wh = Py + E;                    // 1.2 MB
  _Float16* yT = Wh + (size_t)768 * 768;    // 25.2 MB (own buffer; total 127 MB)
  _Float16* alpha = xh;                     // overlays xh (dead after proj)

  static bool attr_set = false;
  if (!attr_set) {
    hipFuncSetAttribute((const void*)proj8_kernel,
                        hipFuncAttributeMaxDynamicSharedMemorySize, 98304);
    attr_set = true;
  }

  dim3 blk(256);
  cvt_xW_kernel<<<dim3(6144 + 288), blk, 0, stream>>>(x, W, xh, Wh);
  cvt_y_yT_kernel<<<dim3(8, 12, 32), blk, 0, stream>>>(y, yh, yT);
  proj8_kernel<<<dim3(64, 6, 2), dim3(512), 98304, stream>>>(xh, yh, Wh, b, Px, Py);
  scores_softmax_kernel<<<dim3(256), dim3(512), 0, stream>>>(Px, Py, y_mask, alpha);
  attn_mfma_kernel<<<dim3(768), blk, 0, stream>>>(alpha, yT, out);
}